// Round 12
// baseline (370.406 us; speedup 1.0000x reference)
//
#include <hip/hip_runtime.h>
#include <math.h>

// ---------------------------------------------------------------------------
// Round 8: depth-4 prefetch pipeline for the latency-bound small GEMMs.
// rgemm: 5 LDS buffers, stages s..s+3 in flight, tail-aware counted vmcnt
// (2*min(3,rem)), no full-drain prologue barrier. LDS 41KB -> 3 blocks/CU.
// attn: 2048 blocks x 4 units/wave (was 8192 x 1). lngemm unchanged (3-buf).
// Math identical to round 4/7 (LN folded; stats piped via epilogues).
// ---------------------------------------------------------------------------

typedef __attribute__((ext_vector_type(8))) short bf16x8;
typedef __attribute__((ext_vector_type(4))) float f32x4;

__device__ __forceinline__ float bf2f(ushort u) {
    union { uint i; float f; } c; c.i = ((uint)u) << 16; return c.f;
}
__device__ __forceinline__ ushort f2bf(float f) {
    union { float f; uint i; } c; c.f = f;
    uint u = c.i + 0x7fffu + ((c.i >> 16) & 1u);   // RNE
    return (ushort)(u >> 16);
}
__device__ __forceinline__ float gelu_f(float v) {
    return 0.5f * v * (1.0f + erff(v * 0.70710678118654752f));
}
__device__ __forceinline__ void gll16(const ushort* g, ushort* l) {
    __builtin_amdgcn_global_load_lds(
        (__attribute__((address_space(1))) void*)g,
        (__attribute__((address_space(3))) void*)l, 16, 0, 0);
}

// ---------------------------------------------------------------------------
// LN-folded GEMM: Cb[M,N](bf16) = epi( rstd*(A@W'^T - mean*c2) + bias2 )
// K = 512 fixed. 3-buf depth-2 pipeline (occupancy-optimal for 128^2 tiles).
// ---------------------------------------------------------------------------
template <int BM, int BN, int MODE>
__device__ __forceinline__ void lngemm_body(
    const ushort* __restrict__ A, const float2* __restrict__ stats, int nslots,
    const ushort* __restrict__ W, const float* __restrict__ bias2,
    const float* __restrict__ c2, ushort* __restrict__ Cb, int N)
{
    constexpr int BK = 32, K = 512, KSTEPS = K / BK;
    constexpr int FM = BM / 32, FN = BN / 32;
    constexpr int NL = BM / 64 + BN / 64;
    __shared__ ushort As[3 * BM * BK];
    __shared__ ushort Bs[3 * BN * BK];
    __shared__ float smean[BM], srstd[BM];

    const int t = threadIdx.x;
    const int lane = t & 63;
    const int w = t >> 6;
    const int wm = (w >> 1) * (BM / 2);
    const int wn = (w & 1) * (BN / 2);
    const int bm = blockIdx.y * BM;
    const int bn = blockIdx.x * BN;
    const int srow = t >> 2;
    const int schunk = ((t & 3) ^ (srow & 3)) * 8;   // pre-swizzled source

    const ushort* Ag = A + (size_t)(bm + srow) * K + schunk;
    const ushort* Wg = W + (size_t)(bn + srow) * K + schunk;
    auto stage = [&](int buf, int k0) {
#pragma unroll
        for (int i = 0; i < BM / 64; ++i)
            gll16(Ag + k0 + (size_t)(i * 64) * K, As + buf * (BM * BK) + i * 2048 + t * 8);
#pragma unroll
        for (int i = 0; i < BN / 64; ++i)
            gll16(Wg + k0 + (size_t)(i * 64) * K, Bs + buf * (BN * BK) + i * 2048 + t * 8);
    };
    stage(0, 0);
    stage(1, BK);

    if (t < BM) {     // per-row LN stats from producer partials
        float S = 0.f, SS = 0.f;
        for (int i = 0; i < nslots; ++i) {
            float2 pp = stats[(size_t)(bm + t) * 8 + i];
            S += pp.x; SS += pp.y;
        }
        const float mean = S * (1.0f / 512.0f);
        const float var  = SS * (1.0f / 512.0f) - mean * mean;
        smean[t] = mean;
        srstd[t] = rsqrtf(var + 1e-5f);
    }
    __syncthreads();   // full drain once: bufs 0,1 + stats resident

    f32x4 acc[FM][FN];
#pragma unroll
    for (int m = 0; m < FM; ++m)
#pragma unroll
        for (int n = 0; n < FN; ++n) acc[m][n] = (f32x4){0.f, 0.f, 0.f, 0.f};
    const int fr = lane & 15;
    const int rchunk = (((lane >> 4) ^ (fr & 3))) * 8;   // swizzled read chunk

    int cur = 0, nxt2 = 2;
    for (int s = 0; s < KSTEPS; ++s) {
        if (s + 1 < KSTEPS) {
            if constexpr (NL == 2) asm volatile("s_waitcnt vmcnt(2)" ::: "memory");
            else                   asm volatile("s_waitcnt vmcnt(4)" ::: "memory");
        } else {
            asm volatile("s_waitcnt vmcnt(0)" ::: "memory");
        }
        __builtin_amdgcn_s_barrier();
        if (s + 2 < KSTEPS) stage(nxt2, (s + 2) * BK);

        const ushort* Ab = As + cur * (BM * BK);
        const ushort* Bb = Bs + cur * (BN * BK);
        bf16x8 af[FM], bv[FN];
#pragma unroll
        for (int m = 0; m < FM; ++m)
            af[m] = *(const bf16x8*)&Ab[(wm + m * 16 + fr) * BK + rchunk];
#pragma unroll
        for (int n = 0; n < FN; ++n)
            bv[n] = *(const bf16x8*)&Bb[(wn + n * 16 + fr) * BK + rchunk];
#pragma unroll
        for (int m = 0; m < FM; ++m)
#pragma unroll
            for (int n = 0; n < FN; ++n)
                acc[m][n] = __builtin_amdgcn_mfma_f32_16x16x32_bf16(
                    af[m], bv[n], acc[m][n], 0, 0, 0);
        cur  = (cur  == 2) ? 0 : cur + 1;
        nxt2 = (nxt2 == 2) ? 0 : nxt2 + 1;
    }

    // epilogue: C/D layout col=lane&15, row=(lane>>4)*4+j
    const int fq = (lane >> 4) * 4;
#pragma unroll
    for (int m = 0; m < FM; ++m) {
#pragma unroll
        for (int n = 0; n < FN; ++n) {
            const int col = bn + wn + n * 16 + fr;
            const float c2v = c2[col];
            const float b2v = bias2[col];
#pragma unroll
            for (int j = 0; j < 4; ++j) {
                const int rloc = wm + m * 16 + fq + j;
                float uu = srstd[rloc] * (acc[m][n][j] - smean[rloc] * c2v) + b2v;
                if (MODE == 1) uu = gelu_f(uu);
                Cb[(size_t)(bm + rloc) * N + col] = f2bf(uu);
            }
        }
    }
}

#define LNG_ARGS const ushort* __restrict__ A, const float2* __restrict__ stats, \
    int nslots, const ushort* __restrict__ W, const float* __restrict__ bias2,   \
    const float* __restrict__ c2, ushort* __restrict__ Cb, int N
#define DEF_LNG(NAME, BM, BN, MODE)                                              \
__global__ __launch_bounds__(256) void NAME(LNG_ARGS) {                          \
    lngemm_body<BM, BN, MODE>(A, stats, nslots, W, bias2, c2, Cb, N);            \
}
DEF_LNG(qkv_g,  128, 128, 0)   // N=1536
DEF_LNG(ff1_g,   64,  64, 1)   // N=512, gelu
DEF_LNG(mlp1_g, 128, 128, 1)   // N=2048, gelu

// ---------------------------------------------------------------------------
// Residual GEMM 64x64: u = A@W^T + bias + res (+res2). Runtime K.
// 5-buffer depth-4 pipeline, tail-aware counted vmcnt, no drain prologue.
// ---------------------------------------------------------------------------
template <bool ADD2, bool STATS>
__device__ __forceinline__ void rgemm_body(
    const ushort* __restrict__ A, const ushort* __restrict__ W,
    const float* __restrict__ bias, const float* __restrict__ res,
    const float* __restrict__ res2, float* __restrict__ Cf,
    ushort* __restrict__ Cbb, float2* __restrict__ statsOut, int N, int K)
{
    constexpr int BM = 64, BN = 64, BK = 32, NBUF = 5;
    __shared__ ushort As[NBUF * BM * BK];
    __shared__ ushort Bs[NBUF * BN * BK];
    __shared__ float2 rowred[BM * 2];

    const int t = threadIdx.x;
    const int lane = t & 63;
    const int w = t >> 6;
    const int wm = (w >> 1) * 32;
    const int wn = (w & 1) * 32;
    const int bm = blockIdx.y * BM;
    const int bn = blockIdx.x * BN;
    const int srow = t >> 2;
    const int schunk = ((t & 3) ^ (srow & 3)) * 8;
    const int ksteps = K / BK;

    const ushort* Ag = A + (size_t)(bm + srow) * K + schunk;
    const ushort* Wg = W + (size_t)(bn + srow) * K + schunk;
    auto stage = [&](int buf, int k0) {
        gll16(Ag + k0, As + buf * 2048 + t * 8);
        gll16(Wg + k0, Bs + buf * 2048 + t * 8);
    };
    // prologue: 4 stages in flight, NO full drain (first counted wait covers it)
    stage(0, 0);
    stage(1, BK);
    stage(2, 2 * BK);
    stage(3, 3 * BK);

    f32x4 acc[2][2];
#pragma unroll
    for (int m = 0; m < 2; ++m)
#pragma unroll
        for (int n = 0; n < 2; ++n) acc[m][n] = (f32x4){0.f, 0.f, 0.f, 0.f};
    const int fr = lane & 15;
    const int rchunk = (((lane >> 4) ^ (fr & 3))) * 8;

    int cb = 0, sb = 4;   // compute buf = s%5, stage buf = (s+4)%5
    for (int s = 0; s < ksteps; ++s) {
        const int rem = ksteps - 1 - s;   // stages issued after stage s
        if (rem >= 3)      asm volatile("s_waitcnt vmcnt(6)" ::: "memory");
        else if (rem == 2) asm volatile("s_waitcnt vmcnt(4)" ::: "memory");
        else if (rem == 1) asm volatile("s_waitcnt vmcnt(2)" ::: "memory");
        else               asm volatile("s_waitcnt vmcnt(0)" ::: "memory");
        __builtin_amdgcn_s_barrier();
        if (s + 4 < ksteps) stage(sb, (s + 4) * BK);

        const ushort* Ab = As + cb * 2048;
        const ushort* Bb = Bs + cb * 2048;
        bf16x8 a0 = *(const bf16x8*)&Ab[(wm + fr) * BK + rchunk];
        bf16x8 a1 = *(const bf16x8*)&Ab[(wm + 16 + fr) * BK + rchunk];
        bf16x8 b0 = *(const bf16x8*)&Bb[(wn + fr) * BK + rchunk];
        bf16x8 b1 = *(const bf16x8*)&Bb[(wn + 16 + fr) * BK + rchunk];
        acc[0][0] = __builtin_amdgcn_mfma_f32_16x16x32_bf16(a0, b0, acc[0][0], 0, 0, 0);
        acc[0][1] = __builtin_amdgcn_mfma_f32_16x16x32_bf16(a0, b1, acc[0][1], 0, 0, 0);
        acc[1][0] = __builtin_amdgcn_mfma_f32_16x16x32_bf16(a1, b0, acc[1][0], 0, 0, 0);
        acc[1][1] = __builtin_amdgcn_mfma_f32_16x16x32_bf16(a1, b1, acc[1][1], 0, 0, 0);
        cb = (cb == NBUF - 1) ? 0 : cb + 1;
        sb = (sb == NBUF - 1) ? 0 : sb + 1;
    }

    const int fq = (lane >> 4) * 4;
    float rs[8], rss[8];
#pragma unroll
    for (int i = 0; i < 8; ++i) { rs[i] = 0.f; rss[i] = 0.f; }

#pragma unroll
    for (int m = 0; m < 2; ++m) {
#pragma unroll
        for (int n = 0; n < 2; ++n) {
            const int col = bn + wn + n * 16 + fr;
            const float bvv = bias[col];
#pragma unroll
            for (int j = 0; j < 4; ++j) {
                const int rloc = wm + m * 16 + fq + j;
                const size_t off = (size_t)(bm + rloc) * N + col;
                float uu = acc[m][n][j] + bvv + res[off];
                if (ADD2) uu += res2[off];
                Cf[off] = uu;
                if (STATS) {
                    Cbb[off] = f2bf(uu);
                    rs[m * 4 + j]  += uu;
                    rss[m * 4 + j] += uu * uu;
                }
            }
        }
    }

    if (STATS) {
#pragma unroll
        for (int i = 0; i < 8; ++i) {
            rs[i]  += __shfl_xor(rs[i], 1);  rs[i]  += __shfl_xor(rs[i], 2);
            rs[i]  += __shfl_xor(rs[i], 4);  rs[i]  += __shfl_xor(rs[i], 8);
            rss[i] += __shfl_xor(rss[i], 1); rss[i] += __shfl_xor(rss[i], 2);
            rss[i] += __shfl_xor(rss[i], 4); rss[i] += __shfl_xor(rss[i], 8);
        }
        __syncthreads();
        if ((lane & 15) == 0) {
#pragma unroll
            for (int m = 0; m < 2; ++m)
#pragma unroll
                for (int j = 0; j < 4; ++j)
                    rowred[(wm + m * 16 + fq + j) * 2 + (w & 1)] =
                        make_float2(rs[m * 4 + j], rss[m * 4 + j]);
        }
        __syncthreads();
        if (t < BM) {
            float2 a = rowred[t * 2], b = rowred[t * 2 + 1];
            statsOut[(size_t)(bm + t) * 8 + blockIdx.x] =
                make_float2(a.x + b.x, a.y + b.y);
        }
    }
}

#define RG_ARGS const ushort* __restrict__ A, const ushort* __restrict__ W,    \
    const float* __restrict__ bias, const float* __restrict__ res,             \
    const float* __restrict__ res2, float* __restrict__ Cf,                    \
    ushort* __restrict__ Cbb, float2* __restrict__ statsOut, int N, int K
#define DEF_RG(NAME, ADD2, STATS)                                              \
__global__ __launch_bounds__(256) void NAME(RG_ARGS) {                         \
    rgemm_body<ADD2, STATS>(A, W, bias, res, res2, Cf, Cbb, statsOut, N, K);   \
}
DEF_RG(outp_g,  false, true)    // attn out-proj + residual
DEF_RG(ff2_g,   false, true)    // ff2 + residual
DEF_RG(ff2l_g,  true,  true)    // layer-3 ff2: + residual + x
DEF_RG(mlp2_g,  false, false)   // final mlp2, K=2048

// Windowed 3x3 attention; 2048 blocks, 4 (token,head) units per wave.
__global__ __launch_bounds__(256) void attn_win_k(
    const ushort* __restrict__ qkv, ushort* __restrict__ o)
{
    const int wid0 = (blockIdx.x * 256 + threadIdx.x) >> 6;   // 0..8191
    const int lane = threadIdx.x & 63;
#pragma unroll
    for (int kk = 0; kk < 4; ++kk) {
        const int wid = wid0 + kk * 8192;
        const int hh = wid & 7;
        const int m  = wid >> 3;
        const int s  = m & 1023;
        const int y  = s >> 5, xq = s & 31;
        const int base_b = m & ~1023;

        const float qd = bf2f(qkv[(size_t)m * 1536 + hh * 64 + lane]);

        float sc[9];
        int   idx[9];
#pragma unroll
        for (int j = 0; j < 9; ++j) {
            const int dy = j / 3 - 1, dx = j % 3 - 1;
            const int yy = y + dy, xx = xq + dx;
            const bool ok = ((unsigned)yy < 32u) && ((unsigned)xx < 32u);
            const int ms = ok ? (base_b + (yy << 5) + xx) : m;
            idx[j] = ms;
            float pv = qd * bf2f(qkv[(size_t)ms * 1536 + 512 + hh * 64 + lane]);
#pragma unroll
            for (int off = 32; off; off >>= 1) pv += __shfl_xor(pv, off);
            sc[j] = ok ? pv * 0.125f : -1e30f;
        }
        float mx = sc[0];
#pragma unroll
        for (int j = 1; j < 9; ++j) mx = fmaxf(mx, sc[j]);
        float sum = 0.0f;
#pragma unroll
        for (int j = 0; j < 9; ++j) { sc[j] = expf(sc[j] - mx); sum += sc[j]; }
        const float inv = 1.0f / sum;
        float od = 0.0f;
#pragma unroll
        for (int j = 0; j < 9; ++j)
            od += sc[j] * bf2f(qkv[(size_t)idx[j] * 1536 + 1024 + hh * 64 + lane]);
        o[(size_t)m * 512 + hh * 64 + lane] = f2bf(od * inv);
    }
}

// Merged weight conversion + x stats/cast. Blocks [0,16384) = cvt units,
// [16384,17408) = stats units.
__global__ __launch_bounds__(256) void cvtstats_k(
    const float* __restrict__ in_w, const float* __restrict__ in_b,
    const float* __restrict__ ln1_g, const float* __restrict__ ln1_b,
    const float* __restrict__ ff1_w, const float* __restrict__ ff1_b,
    const float* __restrict__ ln2_g, const float* __restrict__ ln2_b,
    const float* __restrict__ mlp_w1, const float* __restrict__ mlp_b1,
    const float* __restrict__ mlp_ln_g, const float* __restrict__ mlp_ln_b,
    const float* __restrict__ out_w, const float* __restrict__ ff2_w,
    const float* __restrict__ mlp_w2, ushort* __restrict__ wb,
    float* __restrict__ consts,
    const float* __restrict__ x, ushort* __restrict__ xb,
    float2* __restrict__ so)
{
    const int blk = blockIdx.x, t = threadIdx.x;
    if (blk >= 16384) {   // stats units
        const int u = blk - 16384;
        const int row  = u * 4 + (t >> 6);
        const int lane = t & 63;
        const float* xr = x + (size_t)row * 512 + lane * 8;
        float4 a0 = *(const float4*)xr;
        float4 a1 = *(const float4*)(xr + 4);
        bf16x8 pk;
        pk[0] = (short)f2bf(a0.x); pk[1] = (short)f2bf(a0.y);
        pk[2] = (short)f2bf(a0.z); pk[3] = (short)f2bf(a0.w);
        pk[4] = (short)f2bf(a1.x); pk[5] = (short)f2bf(a1.y);
        pk[6] = (short)f2bf(a1.z); pk[7] = (short)f2bf(a1.w);
        *(bf16x8*)&xb[(size_t)row * 512 + lane * 8] = pk;
        float s  = a0.x + a0.y + a0.z + a0.w + a1.x + a1.y + a1.z + a1.w;
        float ss = a0.x*a0.x + a0.y*a0.y + a0.z*a0.z + a0.w*a0.w
                 + a1.x*a1.x + a1.y*a1.y + a1.z*a1.z + a1.w*a1.w;
#pragma unroll
        for (int off = 32; off; off >>= 1) {
            s  += __shfl_xor(s, off);
            ss += __shfl_xor(ss, off);
        }
        if (lane == 0) so[(size_t)row * 8] = make_float2(s, ss);
        return;
    }
    __shared__ float redA[4], redB[4];
    const float *src, *g = nullptr, *b = nullptr, *bias = nullptr;
    ushort* dst; float *c2o = nullptr, *b2o = nullptr;
    int r = 0;
    if (blk < 6144) {                 // in_w, scaled by ln1_g[l]
        r = blk; const int l = r / 1536;
        src = in_w + (size_t)r * 512; dst = wb + (size_t)r * 512;
        g = ln1_g + l * 512; b = ln1_b + l * 512;
        bias = in_b; c2o = consts + 6144; b2o = consts;
    } else if (blk < 8192) {          // ff1_w, scaled by ln2_g[l]
        r = blk - 6144; const int l = r >> 9;
        src = ff1_w + (size_t)r * 512; dst = wb + 4194304 + (size_t)r * 512;
        g = ln2_g + l * 512; b = ln2_b + l * 512;
        bias = ff1_b; c2o = consts + 14336; b2o = consts + 12288;
    } else if (blk < 10240) {         // mlp_w1, scaled by mlp_ln_g
        r = blk - 8192;
        src = mlp_w1 + (size_t)r * 512; dst = wb + 6291456 + (size_t)r * 512;
        g = mlp_ln_g; b = mlp_ln_b;
        bias = mlp_b1; c2o = consts + 18432; b2o = consts + 16384;
    } else if (blk < 12288) {         // out_w plain
        const int q = blk - 10240;
        src = out_w + (size_t)q * 512; dst = wb + 3145728 + (size_t)q * 512;
    } else if (blk < 14336) {         // ff2_w plain
        const int q = blk - 12288;
        src = ff2_w + (size_t)q * 512; dst = wb + 5242880 + (size_t)q * 512;
    } else {                          // mlp_w2 plain
        const int q = blk - 14336;
        src = mlp_w2 + (size_t)q * 512; dst = wb + 7340032 + (size_t)q * 512;
    }
    float2 wv = *(const float2*)&src[t * 2];
    if (g) {
        float2 gv = *(const float2*)&g[t * 2];
        float2 bv = *(const float2*)&b[t * 2];
        const float w0 = wv.x * gv.x, w1 = wv.y * gv.y;
        ushort2 o; o.x = f2bf(w0); o.y = f2bf(w1);
        *(ushort2*)&dst[t * 2] = o;
        float sc2 = w0 + w1;
        float sc1 = bv.x * wv.x + bv.y * wv.y;
#pragma unroll
        for (int off = 32; off; off >>= 1) {
            sc2 += __shfl_xor(sc2, off);
            sc1 += __shfl_xor(sc1, off);
        }
        const int w_ = t >> 6;
        if ((t & 63) == 0) { redA[w_] = sc2; redB[w_] = sc1; }
        __syncthreads();
        if (t == 0) {
            c2o[r] = redA[0] + redA[1] + redA[2] + redA[3];
            b2o[r] = bias[r] + redB[0] + redB[1] + redB[2] + redB[3];
        }
    } else {
        ushort2 o; o.x = f2bf(wv.x); o.y = f2bf(wv.y);
        *(ushort2*)&dst[t * 2] = o;
    }
}

extern "C" void kernel_launch(void* const* d_in, const int* in_sizes, int n_in,
                              void* d_out, int out_size, void* d_ws, size_t ws_size,
                              hipStream_t stream) {
    const float* x        = (const float*)d_in[0];
    // d_in[1] = mask (unused; window hardcoded)
    const float* in_w     = (const float*)d_in[2];
    const float* in_b     = (const float*)d_in[3];
    const float* out_w    = (const float*)d_in[4];
    const float* out_b    = (const float*)d_in[5];
    const float* ln1_g    = (const float*)d_in[6];
    const float* ln1_b    = (const float*)d_in[7];
    const float* ln2_g    = (const float*)d_in[8];
    const float* ln2_b    = (const float*)d_in[9];
    const float* ff1_w    = (const float*)d_in[10];
    const float* ff1_b    = (const float*)d_in[11];
    const float* ff2_w    = (const float*)d_in[12];
    const float* ff2_b    = (const float*)d_in[13];
    const float* mlp_ln_g = (const float*)d_in[14];
    const float* mlp_ln_b = (const float*)d_in[15];
    const float* mlp_w1   = (const float*)d_in[16];
    const float* mlp_b1   = (const float*)d_in[17];
    const float* mlp_w2   = (const float*)d_in[18];
    const float* mlp_b2   = (const float*)d_in[19];
    float* out = (float*)d_out;

    const int M = 4096, E = 512;

    // ws layout (bytes): [0,16M) bf16 weights | [16M,+) consts |
    // [16.25M) stats_a | [16.5M) stats_b | [17M,25M) cur fp32 |
    // [25M,29M) curb bf16 | [29M,33M) b01 | [33M,45M) big (qkv)
    ushort* wb      = (ushort*)d_ws;
    float*  consts  = (float*)((char*)d_ws + (16u << 20));
    float2* stats_a = (float2*)((char*)d_ws + (16u << 20) + (256u << 10));
    float2* stats_b = stats_a + 32768;
    float*  cur     = (float*)((char*)d_ws + (17u << 20));
    ushort* curb    = (ushort*)((char*)d_ws + (25u << 20));
    ushort* b01     = (ushort*)((char*)d_ws + (29u << 20));
    ushort* big     = (ushort*)((char*)d_ws + (33u << 20));
    ushort* hidden  = b01;      // mlp hidden [M,2048] spans b01+big

    ushort* w_in  = wb;
    ushort* w_out = wb + 3145728;
    ushort* w_ff1 = wb + 4194304;
    ushort* w_ff2 = wb + 5242880;
    ushort* w_m1  = wb + 6291456;
    ushort* w_m2  = wb + 7340032;
    float* bias2_in = consts;            float* c2_in = consts + 6144;
    float* bias2_f1 = consts + 12288;    float* c2_f1 = consts + 14336;
    float* bias2_m1 = consts + 16384;    float* c2_m1 = consts + 18432;

    dim3 blk(256);
    cvtstats_k<<<17408, blk, 0, stream>>>(
        in_w, in_b, ln1_g, ln1_b, ff1_w, ff1_b, ln2_g, ln2_b,
        mlp_w1, mlp_b1, mlp_ln_g, mlp_ln_b, out_w, ff2_w, mlp_w2, wb, consts,
        x, curb, stats_a);

    for (int i = 0; i < 4; ++i) {
        const float* resid = (i == 0) ? x : cur;
        qkv_g<<<dim3(12, 32), blk, 0, stream>>>(
            curb, stats_a, (i == 0) ? 1 : 8,
            w_in + (size_t)i * 786432, bias2_in + i * 1536, c2_in + i * 1536,
            big, 1536);
        attn_win_k<<<2048, blk, 0, stream>>>(big, b01);
        outp_g<<<dim3(8, 64), blk, 0, stream>>>(
            b01, w_out + (size_t)i * 262144, out_b + i * E, resid, nullptr,
            cur, curb, stats_b, E, E);
        ff1_g<<<dim3(8, 64), blk, 0, stream>>>(
            curb, stats_b, 8,
            w_ff1 + (size_t)i * 262144, bias2_f1 + i * E, c2_f1 + i * E,
            b01, E);
        if (i < 3) {
            ff2_g<<<dim3(8, 64), blk, 0, stream>>>(
                b01, w_ff2 + (size_t)i * 262144, ff2_b + i * E, cur, nullptr,
                cur, curb, stats_a, E, E);
        } else {
            ff2l_g<<<dim3(8, 64), blk, 0, stream>>>(
                b01, w_ff2 + (size_t)i * 262144, ff2_b + i * E, cur, x,
                out, curb, stats_a, E, E);
        }
    }

    mlp1_g<<<dim3(16, 32), blk, 0, stream>>>(
        curb, stats_a, 8, w_m1, bias2_m1, c2_m1, hidden, 2048);
    mlp2_g<<<dim3(8, 64), blk, 0, stream>>>(
        hidden, w_m2, mlp_b2, out, nullptr, out, nullptr, nullptr, E, 2048);
}

// Round 13
// 369.673 us; speedup vs baseline: 1.0020x; 1.0020x over previous
//
#include <hip/hip_runtime.h>
#include <math.h>

// ---------------------------------------------------------------------------
// Round 8: depth-4 prefetch pipeline for the latency-bound small GEMMs.
// rgemm: 5 LDS buffers, stages s..s+3 in flight, tail-aware counted vmcnt
// (2*min(3,rem)), no full-drain prologue barrier. LDS 41KB -> 3 blocks/CU.
// attn: 2048 blocks x 4 units/wave (was 8192 x 1). lngemm unchanged (3-buf).
// Math identical to round 4/7 (LN folded; stats piped via epilogues).
// ---------------------------------------------------------------------------

typedef __attribute__((ext_vector_type(8))) short bf16x8;
typedef __attribute__((ext_vector_type(4))) float f32x4;

__device__ __forceinline__ float bf2f(ushort u) {
    union { uint i; float f; } c; c.i = ((uint)u) << 16; return c.f;
}
__device__ __forceinline__ ushort f2bf(float f) {
    union { float f; uint i; } c; c.f = f;
    uint u = c.i + 0x7fffu + ((c.i >> 16) & 1u);   // RNE
    return (ushort)(u >> 16);
}
__device__ __forceinline__ float gelu_f(float v) {
    return 0.5f * v * (1.0f + erff(v * 0.70710678118654752f));
}
__device__ __forceinline__ void gll16(const ushort* g, ushort* l) {
    __builtin_amdgcn_global_load_lds(
        (__attribute__((address_space(1))) void*)g,
        (__attribute__((address_space(3))) void*)l, 16, 0, 0);
}

// ---------------------------------------------------------------------------
// LN-folded GEMM: Cb[M,N](bf16) = epi( rstd*(A@W'^T - mean*c2) + bias2 )
// K = 512 fixed. 3-buf depth-2 pipeline (occupancy-optimal for 128^2 tiles).
// ---------------------------------------------------------------------------
template <int BM, int BN, int MODE>
__device__ __forceinline__ void lngemm_body(
    const ushort* __restrict__ A, const float2* __restrict__ stats, int nslots,
    const ushort* __restrict__ W, const float* __restrict__ bias2,
    const float* __restrict__ c2, ushort* __restrict__ Cb, int N)
{
    constexpr int BK = 32, K = 512, KSTEPS = K / BK;
    constexpr int FM = BM / 32, FN = BN / 32;
    constexpr int NL = BM / 64 + BN / 64;
    __shared__ ushort As[3 * BM * BK];
    __shared__ ushort Bs[3 * BN * BK];
    __shared__ float smean[BM], srstd[BM];

    const int t = threadIdx.x;
    const int lane = t & 63;
    const int w = t >> 6;
    const int wm = (w >> 1) * (BM / 2);
    const int wn = (w & 1) * (BN / 2);
    const int bm = blockIdx.y * BM;
    const int bn = blockIdx.x * BN;
    const int srow = t >> 2;
    const int schunk = ((t & 3) ^ (srow & 3)) * 8;   // pre-swizzled source

    const ushort* Ag = A + (size_t)(bm + srow) * K + schunk;
    const ushort* Wg = W + (size_t)(bn + srow) * K + schunk;
    auto stage = [&](int buf, int k0) {
#pragma unroll
        for (int i = 0; i < BM / 64; ++i)
            gll16(Ag + k0 + (size_t)(i * 64) * K, As + buf * (BM * BK) + i * 2048 + t * 8);
#pragma unroll
        for (int i = 0; i < BN / 64; ++i)
            gll16(Wg + k0 + (size_t)(i * 64) * K, Bs + buf * (BN * BK) + i * 2048 + t * 8);
    };
    stage(0, 0);
    stage(1, BK);

    if (t < BM) {     // per-row LN stats from producer partials
        float S = 0.f, SS = 0.f;
        for (int i = 0; i < nslots; ++i) {
            float2 pp = stats[(size_t)(bm + t) * 8 + i];
            S += pp.x; SS += pp.y;
        }
        const float mean = S * (1.0f / 512.0f);
        const float var  = SS * (1.0f / 512.0f) - mean * mean;
        smean[t] = mean;
        srstd[t] = rsqrtf(var + 1e-5f);
    }
    __syncthreads();   // full drain once: bufs 0,1 + stats resident

    f32x4 acc[FM][FN];
#pragma unroll
    for (int m = 0; m < FM; ++m)
#pragma unroll
        for (int n = 0; n < FN; ++n) acc[m][n] = (f32x4){0.f, 0.f, 0.f, 0.f};
    const int fr = lane & 15;
    const int rchunk = (((lane >> 4) ^ (fr & 3))) * 8;   // swizzled read chunk

    int cur = 0, nxt2 = 2;
    for (int s = 0; s < KSTEPS; ++s) {
        if (s + 1 < KSTEPS) {
            if constexpr (NL == 2) asm volatile("s_waitcnt vmcnt(2)" ::: "memory");
            else                   asm volatile("s_waitcnt vmcnt(4)" ::: "memory");
        } else {
            asm volatile("s_waitcnt vmcnt(0)" ::: "memory");
        }
        __builtin_amdgcn_s_barrier();
        if (s + 2 < KSTEPS) stage(nxt2, (s + 2) * BK);

        const ushort* Ab = As + cur * (BM * BK);
        const ushort* Bb = Bs + cur * (BN * BK);
        bf16x8 af[FM], bv[FN];
#pragma unroll
        for (int m = 0; m < FM; ++m)
            af[m] = *(const bf16x8*)&Ab[(wm + m * 16 + fr) * BK + rchunk];
#pragma unroll
        for (int n = 0; n < FN; ++n)
            bv[n] = *(const bf16x8*)&Bb[(wn + n * 16 + fr) * BK + rchunk];
#pragma unroll
        for (int m = 0; m < FM; ++m)
#pragma unroll
            for (int n = 0; n < FN; ++n)
                acc[m][n] = __builtin_amdgcn_mfma_f32_16x16x32_bf16(
                    af[m], bv[n], acc[m][n], 0, 0, 0);
        cur  = (cur  == 2) ? 0 : cur + 1;
        nxt2 = (nxt2 == 2) ? 0 : nxt2 + 1;
    }

    // epilogue: C/D layout col=lane&15, row=(lane>>4)*4+j
    const int fq = (lane >> 4) * 4;
#pragma unroll
    for (int m = 0; m < FM; ++m) {
#pragma unroll
        for (int n = 0; n < FN; ++n) {
            const int col = bn + wn + n * 16 + fr;
            const float c2v = c2[col];
            const float b2v = bias2[col];
#pragma unroll
            for (int j = 0; j < 4; ++j) {
                const int rloc = wm + m * 16 + fq + j;
                float uu = srstd[rloc] * (acc[m][n][j] - smean[rloc] * c2v) + b2v;
                if (MODE == 1) uu = gelu_f(uu);
                Cb[(size_t)(bm + rloc) * N + col] = f2bf(uu);
            }
        }
    }
}

#define LNG_ARGS const ushort* __restrict__ A, const float2* __restrict__ stats, \
    int nslots, const ushort* __restrict__ W, const float* __restrict__ bias2,   \
    const float* __restrict__ c2, ushort* __restrict__ Cb, int N
#define DEF_LNG(NAME, BM, BN, MODE)                                              \
__global__ __launch_bounds__(256) void NAME(LNG_ARGS) {                          \
    lngemm_body<BM, BN, MODE>(A, stats, nslots, W, bias2, c2, Cb, N);            \
}
DEF_LNG(qkv_g,  128, 128, 0)   // N=1536
DEF_LNG(ff1_g,   64,  64, 1)   // N=512, gelu
DEF_LNG(mlp1_g, 128, 128, 1)   // N=2048, gelu

// ---------------------------------------------------------------------------
// Residual GEMM 64x64: u = A@W^T + bias + res (+res2). Runtime K.
// 5-buffer depth-4 pipeline, tail-aware counted vmcnt, no drain prologue.
// ---------------------------------------------------------------------------
template <bool ADD2, bool STATS>
__device__ __forceinline__ void rgemm_body(
    const ushort* __restrict__ A, const ushort* __restrict__ W,
    const float* __restrict__ bias, const float* __restrict__ res,
    const float* __restrict__ res2, float* __restrict__ Cf,
    ushort* __restrict__ Cbb, float2* __restrict__ statsOut, int N, int K)
{
    constexpr int BM = 64, BN = 64, BK = 32, NBUF = 5;
    __shared__ ushort As[NBUF * BM * BK];
    __shared__ ushort Bs[NBUF * BN * BK];
    __shared__ float2 rowred[BM * 2];

    const int t = threadIdx.x;
    const int lane = t & 63;
    const int w = t >> 6;
    const int wm = (w >> 1) * 32;
    const int wn = (w & 1) * 32;
    const int bm = blockIdx.y * BM;
    const int bn = blockIdx.x * BN;
    const int srow = t >> 2;
    const int schunk = ((t & 3) ^ (srow & 3)) * 8;
    const int ksteps = K / BK;

    const ushort* Ag = A + (size_t)(bm + srow) * K + schunk;
    const ushort* Wg = W + (size_t)(bn + srow) * K + schunk;
    auto stage = [&](int buf, int k0) {
        gll16(Ag + k0, As + buf * 2048 + t * 8);
        gll16(Wg + k0, Bs + buf * 2048 + t * 8);
    };
    // prologue: 4 stages in flight, NO full drain (first counted wait covers it)
    stage(0, 0);
    stage(1, BK);
    stage(2, 2 * BK);
    stage(3, 3 * BK);

    f32x4 acc[2][2];
#pragma unroll
    for (int m = 0; m < 2; ++m)
#pragma unroll
        for (int n = 0; n < 2; ++n) acc[m][n] = (f32x4){0.f, 0.f, 0.f, 0.f};
    const int fr = lane & 15;
    const int rchunk = (((lane >> 4) ^ (fr & 3))) * 8;

    int cb = 0, sb = 4;   // compute buf = s%5, stage buf = (s+4)%5
    for (int s = 0; s < ksteps; ++s) {
        const int rem = ksteps - 1 - s;   // stages issued after stage s
        if (rem >= 3)      asm volatile("s_waitcnt vmcnt(6)" ::: "memory");
        else if (rem == 2) asm volatile("s_waitcnt vmcnt(4)" ::: "memory");
        else if (rem == 1) asm volatile("s_waitcnt vmcnt(2)" ::: "memory");
        else               asm volatile("s_waitcnt vmcnt(0)" ::: "memory");
        __builtin_amdgcn_s_barrier();
        if (s + 4 < ksteps) stage(sb, (s + 4) * BK);

        const ushort* Ab = As + cb * 2048;
        const ushort* Bb = Bs + cb * 2048;
        bf16x8 a0 = *(const bf16x8*)&Ab[(wm + fr) * BK + rchunk];
        bf16x8 a1 = *(const bf16x8*)&Ab[(wm + 16 + fr) * BK + rchunk];
        bf16x8 b0 = *(const bf16x8*)&Bb[(wn + fr) * BK + rchunk];
        bf16x8 b1 = *(const bf16x8*)&Bb[(wn + 16 + fr) * BK + rchunk];
        acc[0][0] = __builtin_amdgcn_mfma_f32_16x16x32_bf16(a0, b0, acc[0][0], 0, 0, 0);
        acc[0][1] = __builtin_amdgcn_mfma_f32_16x16x32_bf16(a0, b1, acc[0][1], 0, 0, 0);
        acc[1][0] = __builtin_amdgcn_mfma_f32_16x16x32_bf16(a1, b0, acc[1][0], 0, 0, 0);
        acc[1][1] = __builtin_amdgcn_mfma_f32_16x16x32_bf16(a1, b1, acc[1][1], 0, 0, 0);
        cb = (cb == NBUF - 1) ? 0 : cb + 1;
        sb = (sb == NBUF - 1) ? 0 : sb + 1;
    }

    const int fq = (lane >> 4) * 4;
    float rs[8], rss[8];
#pragma unroll
    for (int i = 0; i < 8; ++i) { rs[i] = 0.f; rss[i] = 0.f; }

#pragma unroll
    for (int m = 0; m < 2; ++m) {
#pragma unroll
        for (int n = 0; n < 2; ++n) {
            const int col = bn + wn + n * 16 + fr;
            const float bvv = bias[col];
#pragma unroll
            for (int j = 0; j < 4; ++j) {
                const int rloc = wm + m * 16 + fq + j;
                const size_t off = (size_t)(bm + rloc) * N + col;
                float uu = acc[m][n][j] + bvv + res[off];
                if (ADD2) uu += res2[off];
                Cf[off] = uu;
                if (STATS) {
                    Cbb[off] = f2bf(uu);
                    rs[m * 4 + j]  += uu;
                    rss[m * 4 + j] += uu * uu;
                }
            }
        }
    }

    if (STATS) {
#pragma unroll
        for (int i = 0; i < 8; ++i) {
            rs[i]  += __shfl_xor(rs[i], 1);  rs[i]  += __shfl_xor(rs[i], 2);
            rs[i]  += __shfl_xor(rs[i], 4);  rs[i]  += __shfl_xor(rs[i], 8);
            rss[i] += __shfl_xor(rss[i], 1); rss[i] += __shfl_xor(rss[i], 2);
            rss[i] += __shfl_xor(rss[i], 4); rss[i] += __shfl_xor(rss[i], 8);
        }
        __syncthreads();
        if ((lane & 15) == 0) {
#pragma unroll
            for (int m = 0; m < 2; ++m)
#pragma unroll
                for (int j = 0; j < 4; ++j)
                    rowred[(wm + m * 16 + fq + j) * 2 + (w & 1)] =
                        make_float2(rs[m * 4 + j], rss[m * 4 + j]);
        }
        __syncthreads();
        if (t < BM) {
            float2 a = rowred[t * 2], b = rowred[t * 2 + 1];
            statsOut[(size_t)(bm + t) * 8 + blockIdx.x] =
                make_float2(a.x + b.x, a.y + b.y);
        }
    }
}

#define RG_ARGS const ushort* __restrict__ A, const ushort* __restrict__ W,    \
    const float* __restrict__ bias, const float* __restrict__ res,             \
    const float* __restrict__ res2, float* __restrict__ Cf,                    \
    ushort* __restrict__ Cbb, float2* __restrict__ statsOut, int N, int K
#define DEF_RG(NAME, ADD2, STATS)                                              \
__global__ __launch_bounds__(256) void NAME(RG_ARGS) {                         \
    rgemm_body<ADD2, STATS>(A, W, bias, res, res2, Cf, Cbb, statsOut, N, K);   \
}
DEF_RG(outp_g,  false, true)    // attn out-proj + residual
DEF_RG(ff2_g,   false, true)    // ff2 + residual
DEF_RG(ff2l_g,  true,  true)    // layer-3 ff2: + residual + x
DEF_RG(mlp2_g,  false, false)   // final mlp2, K=2048

// Windowed 3x3 attention; 2048 blocks, 4 (token,head) units per wave.
__global__ __launch_bounds__(256) void attn_win_k(
    const ushort* __restrict__ qkv, ushort* __restrict__ o)
{
    const int wid0 = (blockIdx.x * 256 + threadIdx.x) >> 6;   // 0..8191
    const int lane = threadIdx.x & 63;
#pragma unroll
    for (int kk = 0; kk < 4; ++kk) {
        const int wid = wid0 + kk * 8192;
        const int hh = wid & 7;
        const int m  = wid >> 3;
        const int s  = m & 1023;
        const int y  = s >> 5, xq = s & 31;
        const int base_b = m & ~1023;

        const float qd = bf2f(qkv[(size_t)m * 1536 + hh * 64 + lane]);

        float sc[9];
        int   idx[9];
#pragma unroll
        for (int j = 0; j < 9; ++j) {
            const int dy = j / 3 - 1, dx = j % 3 - 1;
            const int yy = y + dy, xx = xq + dx;
            const bool ok = ((unsigned)yy < 32u) && ((unsigned)xx < 32u);
            const int ms = ok ? (base_b + (yy << 5) + xx) : m;
            idx[j] = ms;
            float pv = qd * bf2f(qkv[(size_t)ms * 1536 + 512 + hh * 64 + lane]);
#pragma unroll
            for (int off = 32; off; off >>= 1) pv += __shfl_xor(pv, off);
            sc[j] = ok ? pv * 0.125f : -1e30f;
        }
        float mx = sc[0];
#pragma unroll
        for (int j = 1; j < 9; ++j) mx = fmaxf(mx, sc[j]);
        float sum = 0.0f;
#pragma unroll
        for (int j = 0; j < 9; ++j) { sc[j] = expf(sc[j] - mx); sum += sc[j]; }
        const float inv = 1.0f / sum;
        float od = 0.0f;
#pragma unroll
        for (int j = 0; j < 9; ++j)
            od += sc[j] * bf2f(qkv[(size_t)idx[j] * 1536 + 1024 + hh * 64 + lane]);
        o[(size_t)m * 512 + hh * 64 + lane] = f2bf(od * inv);
    }
}

// Merged weight conversion + x stats/cast. Blocks [0,16384) = cvt units,
// [16384,17408) = stats units.
__global__ __launch_bounds__(256) void cvtstats_k(
    const float* __restrict__ in_w, const float* __restrict__ in_b,
    const float* __restrict__ ln1_g, const float* __restrict__ ln1_b,
    const float* __restrict__ ff1_w, const float* __restrict__ ff1_b,
    const float* __restrict__ ln2_g, const float* __restrict__ ln2_b,
    const float* __restrict__ mlp_w1, const float* __restrict__ mlp_b1,
    const float* __restrict__ mlp_ln_g, const float* __restrict__ mlp_ln_b,
    const float* __restrict__ out_w, const float* __restrict__ ff2_w,
    const float* __restrict__ mlp_w2, ushort* __restrict__ wb,
    float* __restrict__ consts,
    const float* __restrict__ x, ushort* __restrict__ xb,
    float2* __restrict__ so)
{
    const int blk = blockIdx.x, t = threadIdx.x;
    if (blk >= 16384) {   // stats units
        const int u = blk - 16384;
        const int row  = u * 4 + (t >> 6);
        const int lane = t & 63;
        const float* xr = x + (size_t)row * 512 + lane * 8;
        float4 a0 = *(const float4*)xr;
        float4 a1 = *(const float4*)(xr + 4);
        bf16x8 pk;
        pk[0] = (short)f2bf(a0.x); pk[1] = (short)f2bf(a0.y);
        pk[2] = (short)f2bf(a0.z); pk[3] = (short)f2bf(a0.w);
        pk[4] = (short)f2bf(a1.x); pk[5] = (short)f2bf(a1.y);
        pk[6] = (short)f2bf(a1.z); pk[7] = (short)f2bf(a1.w);
        *(bf16x8*)&xb[(size_t)row * 512 + lane * 8] = pk;
        float s  = a0.x + a0.y + a0.z + a0.w + a1.x + a1.y + a1.z + a1.w;
        float ss = a0.x*a0.x + a0.y*a0.y + a0.z*a0.z + a0.w*a0.w
                 + a1.x*a1.x + a1.y*a1.y + a1.z*a1.z + a1.w*a1.w;
#pragma unroll
        for (int off = 32; off; off >>= 1) {
            s  += __shfl_xor(s, off);
            ss += __shfl_xor(ss, off);
        }
        if (lane == 0) so[(size_t)row * 8] = make_float2(s, ss);
        return;
    }
    __shared__ float redA[4], redB[4];
    const float *src, *g = nullptr, *b = nullptr, *bias = nullptr;
    ushort* dst; float *c2o = nullptr, *b2o = nullptr;
    int r = 0;
    if (blk < 6144) {                 // in_w, scaled by ln1_g[l]
        r = blk; const int l = r / 1536;
        src = in_w + (size_t)r * 512; dst = wb + (size_t)r * 512;
        g = ln1_g + l * 512; b = ln1_b + l * 512;
        bias = in_b; c2o = consts + 6144; b2o = consts;
    } else if (blk < 8192) {          // ff1_w, scaled by ln2_g[l]
        r = blk - 6144; const int l = r >> 9;
        src = ff1_w + (size_t)r * 512; dst = wb + 4194304 + (size_t)r * 512;
        g = ln2_g + l * 512; b = ln2_b + l * 512;
        bias = ff1_b; c2o = consts + 14336; b2o = consts + 12288;
    } else if (blk < 10240) {         // mlp_w1, scaled by mlp_ln_g
        r = blk - 8192;
        src = mlp_w1 + (size_t)r * 512; dst = wb + 6291456 + (size_t)r * 512;
        g = mlp_ln_g; b = mlp_ln_b;
        bias = mlp_b1; c2o = consts + 18432; b2o = consts + 16384;
    } else if (blk < 12288) {         // out_w plain
        const int q = blk - 10240;
        src = out_w + (size_t)q * 512; dst = wb + 3145728 + (size_t)q * 512;
    } else if (blk < 14336) {         // ff2_w plain
        const int q = blk - 12288;
        src = ff2_w + (size_t)q * 512; dst = wb + 5242880 + (size_t)q * 512;
    } else {                          // mlp_w2 plain
        const int q = blk - 14336;
        src = mlp_w2 + (size_t)q * 512; dst = wb + 7340032 + (size_t)q * 512;
    }
    float2 wv = *(const float2*)&src[t * 2];
    if (g) {
        float2 gv = *(const float2*)&g[t * 2];
        float2 bv = *(const float2*)&b[t * 2];
        const float w0 = wv.x * gv.x, w1 = wv.y * gv.y;
        ushort2 o; o.x = f2bf(w0); o.y = f2bf(w1);
        *(ushort2*)&dst[t * 2] = o;
        float sc2 = w0 + w1;
        float sc1 = bv.x * wv.x + bv.y * wv.y;
#pragma unroll
        for (int off = 32; off; off >>= 1) {
            sc2 += __shfl_xor(sc2, off);
            sc1 += __shfl_xor(sc1, off);
        }
        const int w_ = t >> 6;
        if ((t & 63) == 0) { redA[w_] = sc2; redB[w_] = sc1; }
        __syncthreads();
        if (t == 0) {
            c2o[r] = redA[0] + redA[1] + redA[2] + redA[3];
            b2o[r] = bias[r] + redB[0] + redB[1] + redB[2] + redB[3];
        }
    } else {
        ushort2 o; o.x = f2bf(wv.x); o.y = f2bf(wv.y);
        *(ushort2*)&dst[t * 2] = o;
    }
}

extern "C" void kernel_launch(void* const* d_in, const int* in_sizes, int n_in,
                              void* d_out, int out_size, void* d_ws, size_t ws_size,
                              hipStream_t stream) {
    const float* x        = (const float*)d_in[0];
    // d_in[1] = mask (unused; window hardcoded)
    const float* in_w     = (const float*)d_in[2];
    const float* in_b     = (const float*)d_in[3];
    const float* out_w    = (const float*)d_in[4];
    const float* out_b    = (const float*)d_in[5];
    const float* ln1_g    = (const float*)d_in[6];
    const float* ln1_b    = (const float*)d_in[7];
    const float* ln2_g    = (const float*)d_in[8];
    const float* ln2_b    = (const float*)d_in[9];
    const float* ff1_w    = (const float*)d_in[10];
    const float* ff1_b    = (const float*)d_in[11];
    const float* ff2_w    = (const float*)d_in[12];
    const float* ff2_b    = (const float*)d_in[13];
    const float* mlp_ln_g = (const float*)d_in[14];
    const float* mlp_ln_b = (const float*)d_in[15];
    const float* mlp_w1   = (const float*)d_in[16];
    const float* mlp_b1   = (const float*)d_in[17];
    const float* mlp_w2   = (const float*)d_in[18];
    const float* mlp_b2   = (const float*)d_in[19];
    float* out = (float*)d_out;

    const int M = 4096, E = 512;

    // ws layout (bytes): [0,16M) bf16 weights | [16M,+) consts |
    // [16.25M) stats_a | [16.5M) stats_b | [17M,25M) cur fp32 |
    // [25M,29M) curb bf16 | [29M,33M) b01 | [33M,45M) big (qkv)
    ushort* wb      = (ushort*)d_ws;
    float*  consts  = (float*)((char*)d_ws + (16u << 20));
    float2* stats_a = (float2*)((char*)d_ws + (16u << 20) + (256u << 10));
    float2* stats_b = stats_a + 32768;
    float*  cur     = (float*)((char*)d_ws + (17u << 20));
    ushort* curb    = (ushort*)((char*)d_ws + (25u << 20));
    ushort* b01     = (ushort*)((char*)d_ws + (29u << 20));
    ushort* big     = (ushort*)((char*)d_ws + (33u << 20));
    ushort* hidden  = b01;      // mlp hidden [M,2048] spans b01+big

    ushort* w_in  = wb;
    ushort* w_out = wb + 3145728;
    ushort* w_ff1 = wb + 4194304;
    ushort* w_ff2 = wb + 5242880;
    ushort* w_m1  = wb + 6291456;
    ushort* w_m2  = wb + 7340032;
    float* bias2_in = consts;            float* c2_in = consts + 6144;
    float* bias2_f1 = consts + 12288;    float* c2_f1 = consts + 14336;
    float* bias2_m1 = consts + 16384;    float* c2_m1 = consts + 18432;

    dim3 blk(256);
    cvtstats_k<<<17408, blk, 0, stream>>>(
        in_w, in_b, ln1_g, ln1_b, ff1_w, ff1_b, ln2_g, ln2_b,
        mlp_w1, mlp_b1, mlp_ln_g, mlp_ln_b, out_w, ff2_w, mlp_w2, wb, consts,
        x, curb, stats_a);

    for (int i = 0; i < 4; ++i) {
        const float* resid = (i == 0) ? x : cur;
        qkv_g<<<dim3(12, 32), blk, 0, stream>>>(
            curb, stats_a, (i == 0) ? 1 : 8,
            w_in + (size_t)i * 786432, bias2_in + i * 1536, c2_in + i * 1536,
            big, 1536);
        attn_win_k<<<2048, blk, 0, stream>>>(big, b01);
        outp_g<<<dim3(8, 64), blk, 0, stream>>>(
            b01, w_out + (size_t)i * 262144, out_b + i * E, resid, nullptr,
            cur, curb, stats_b, E, E);
        ff1_g<<<dim3(8, 64), blk, 0, stream>>>(
            curb, stats_b, 8,
            w_ff1 + (size_t)i * 262144, bias2_f1 + i * E, c2_f1 + i * E,
            b01, E);
        if (i < 3) {
            ff2_g<<<dim3(8, 64), blk, 0, stream>>>(
                b01, w_ff2 + (size_t)i * 262144, ff2_b + i * E, cur, nullptr,
                cur, curb, stats_a, E, E);
        } else {
            ff2l_g<<<dim3(8, 64), blk, 0, stream>>>(
                b01, w_ff2 + (size_t)i * 262144, ff2_b + i * E, cur, x,
                out, curb, stats_a, E, E);
        }
    }

    mlp1_g<<<dim3(16, 32), blk, 0, stream>>>(
        curb, stats_a, 8, w_m1, bias2_m1, c2_m1, hidden, 2048);
    mlp2_g<<<dim3(8, 64), blk, 0, stream>>>(
        hidden, w_m2, mlp_b2, out, nullptr, out, nullptr, nullptr, E, 2048);
}

// Round 14
// 347.244 us; speedup vs baseline: 1.0667x; 1.0646x over previous
//
#include <hip/hip_runtime.h>
#include <math.h>

// ---------------------------------------------------------------------------
// Round 9: revert round-8 regressions (5-buf rgemm halved occupancy 6->3
// blocks/CU; attn 4-unit serial waves cut TLP 4x). Base = proven round-7.
// One change: qkv/mlp1 tiles 128x128 -> 64x128 (grid 384->768 / 512->1024
// blocks, 1.5->3 / 2->4 blocks/CU). Counted wait generalized: vmcnt(NL)
// where NL = loads/stage (3 for 64x128), vmcnt(0) only on the last step.
// Math identical to round 4/7 (LN folded; stats piped via epilogues).
// ---------------------------------------------------------------------------

typedef __attribute__((ext_vector_type(8))) short bf16x8;
typedef __attribute__((ext_vector_type(4))) float f32x4;

__device__ __forceinline__ float bf2f(ushort u) {
    union { uint i; float f; } c; c.i = ((uint)u) << 16; return c.f;
}
__device__ __forceinline__ ushort f2bf(float f) {
    union { float f; uint i; } c; c.f = f;
    uint u = c.i + 0x7fffu + ((c.i >> 16) & 1u);   // RNE
    return (ushort)(u >> 16);
}
__device__ __forceinline__ float gelu_f(float v) {
    return 0.5f * v * (1.0f + erff(v * 0.70710678118654752f));
}
__device__ __forceinline__ void gll16(const ushort* g, ushort* l) {
    __builtin_amdgcn_global_load_lds(
        (__attribute__((address_space(1))) void*)g,
        (__attribute__((address_space(3))) void*)l, 16, 0, 0);
}

// ---------------------------------------------------------------------------
// LN-folded GEMM: Cb[M,N](bf16) = epi( rstd*(A@W'^T - mean*c2) + bias2 )
// K = 512 fixed. 3-buf depth-2 counted-vmcnt pipeline, swizzled reads.
// ---------------------------------------------------------------------------
template <int BM, int BN, int MODE>
__device__ __forceinline__ void lngemm_body(
    const ushort* __restrict__ A, const float2* __restrict__ stats, int nslots,
    const ushort* __restrict__ W, const float* __restrict__ bias2,
    const float* __restrict__ c2, ushort* __restrict__ Cb, int N)
{
    constexpr int BK = 32, K = 512, KSTEPS = K / BK;
    constexpr int FM = BM / 32, FN = BN / 32;
    constexpr int NL = BM / 64 + BN / 64;
    __shared__ ushort As[3 * BM * BK];
    __shared__ ushort Bs[3 * BN * BK];
    __shared__ float smean[BM], srstd[BM];

    const int t = threadIdx.x;
    const int lane = t & 63;
    const int w = t >> 6;
    const int wm = (w >> 1) * (BM / 2);
    const int wn = (w & 1) * (BN / 2);
    const int bm = blockIdx.y * BM;
    const int bn = blockIdx.x * BN;
    const int srow = t >> 2;
    const int schunk = ((t & 3) ^ (srow & 3)) * 8;   // pre-swizzled source

    const ushort* Ag = A + (size_t)(bm + srow) * K + schunk;
    const ushort* Wg = W + (size_t)(bn + srow) * K + schunk;
    auto stage = [&](int buf, int k0) {
#pragma unroll
        for (int i = 0; i < BM / 64; ++i)
            gll16(Ag + k0 + (size_t)(i * 64) * K, As + buf * (BM * BK) + i * 2048 + t * 8);
#pragma unroll
        for (int i = 0; i < BN / 64; ++i)
            gll16(Wg + k0 + (size_t)(i * 64) * K, Bs + buf * (BN * BK) + i * 2048 + t * 8);
    };
    stage(0, 0);
    stage(1, BK);

    if (t < BM) {     // per-row LN stats from producer partials
        float S = 0.f, SS = 0.f;
        for (int i = 0; i < nslots; ++i) {
            float2 pp = stats[(size_t)(bm + t) * 8 + i];
            S += pp.x; SS += pp.y;
        }
        const float mean = S * (1.0f / 512.0f);
        const float var  = SS * (1.0f / 512.0f) - mean * mean;
        smean[t] = mean;
        srstd[t] = rsqrtf(var + 1e-5f);
    }
    __syncthreads();   // full drain once: bufs 0,1 + stats resident

    f32x4 acc[FM][FN];
#pragma unroll
    for (int m = 0; m < FM; ++m)
#pragma unroll
        for (int n = 0; n < FN; ++n) acc[m][n] = (f32x4){0.f, 0.f, 0.f, 0.f};
    const int fr = lane & 15;
    const int rchunk = (((lane >> 4) ^ (fr & 3))) * 8;   // swizzled read chunk

    int cur = 0, nxt2 = 2;
    for (int s = 0; s < KSTEPS; ++s) {
        if (s + 1 < KSTEPS) {
            // wait until the oldest in-flight stage (NL loads) is retired
            if constexpr (NL == 2)      asm volatile("s_waitcnt vmcnt(2)" ::: "memory");
            else if constexpr (NL == 3) asm volatile("s_waitcnt vmcnt(3)" ::: "memory");
            else                        asm volatile("s_waitcnt vmcnt(4)" ::: "memory");
        } else {
            asm volatile("s_waitcnt vmcnt(0)" ::: "memory");
        }
        __builtin_amdgcn_s_barrier();
        if (s + 2 < KSTEPS) stage(nxt2, (s + 2) * BK);

        const ushort* Ab = As + cur * (BM * BK);
        const ushort* Bb = Bs + cur * (BN * BK);
        bf16x8 af[FM], bv[FN];
#pragma unroll
        for (int m = 0; m < FM; ++m)
            af[m] = *(const bf16x8*)&Ab[(wm + m * 16 + fr) * BK + rchunk];
#pragma unroll
        for (int n = 0; n < FN; ++n)
            bv[n] = *(const bf16x8*)&Bb[(wn + n * 16 + fr) * BK + rchunk];
#pragma unroll
        for (int m = 0; m < FM; ++m)
#pragma unroll
            for (int n = 0; n < FN; ++n)
                acc[m][n] = __builtin_amdgcn_mfma_f32_16x16x32_bf16(
                    af[m], bv[n], acc[m][n], 0, 0, 0);
        cur  = (cur  == 2) ? 0 : cur + 1;
        nxt2 = (nxt2 == 2) ? 0 : nxt2 + 1;
    }

    // epilogue: C/D layout col=lane&15, row=(lane>>4)*4+j
    const int fq = (lane >> 4) * 4;
#pragma unroll
    for (int m = 0; m < FM; ++m) {
#pragma unroll
        for (int n = 0; n < FN; ++n) {
            const int col = bn + wn + n * 16 + fr;
            const float c2v = c2[col];
            const float b2v = bias2[col];
#pragma unroll
            for (int j = 0; j < 4; ++j) {
                const int rloc = wm + m * 16 + fq + j;
                float uu = srstd[rloc] * (acc[m][n][j] - smean[rloc] * c2v) + b2v;
                if (MODE == 1) uu = gelu_f(uu);
                Cb[(size_t)(bm + rloc) * N + col] = f2bf(uu);
            }
        }
    }
}

#define LNG_ARGS const ushort* __restrict__ A, const float2* __restrict__ stats, \
    int nslots, const ushort* __restrict__ W, const float* __restrict__ bias2,   \
    const float* __restrict__ c2, ushort* __restrict__ Cb, int N
#define DEF_LNG(NAME, BM, BN, MODE)                                              \
__global__ __launch_bounds__(256) void NAME(LNG_ARGS) {                          \
    lngemm_body<BM, BN, MODE>(A, stats, nslots, W, bias2, c2, Cb, N);            \
}
DEF_LNG(qkv_g,   64, 128, 0)   // N=1536, 768 blocks (3/CU)
DEF_LNG(ff1_g,   64,  64, 1)   // N=512, gelu
DEF_LNG(mlp1_g,  64, 128, 1)   // N=2048, gelu, 1024 blocks (4/CU)

// ---------------------------------------------------------------------------
// Residual GEMM 64x64: u = A@W^T + bias + res (+res2). Runtime K.
// Round-7 proven config: 3-buf depth-2, 25KB LDS -> 6 blocks/CU.
// ---------------------------------------------------------------------------
template <bool ADD2, bool STATS>
__device__ __forceinline__ void rgemm_body(
    const ushort* __restrict__ A, const ushort* __restrict__ W,
    const float* __restrict__ bias, const float* __restrict__ res,
    const float* __restrict__ res2, float* __restrict__ Cf,
    ushort* __restrict__ Cbb, float2* __restrict__ statsOut, int N, int K)
{
    constexpr int BM = 64, BN = 64, BK = 32;
    __shared__ ushort As[3 * BM * BK];
    __shared__ ushort Bs[3 * BN * BK];
    __shared__ float2 rowred[BM * 2];

    const int t = threadIdx.x;
    const int lane = t & 63;
    const int w = t >> 6;
    const int wm = (w >> 1) * 32;
    const int wn = (w & 1) * 32;
    const int bm = blockIdx.y * BM;
    const int bn = blockIdx.x * BN;
    const int srow = t >> 2;
    const int schunk = ((t & 3) ^ (srow & 3)) * 8;
    const int ksteps = K / BK;

    const ushort* Ag = A + (size_t)(bm + srow) * K + schunk;
    const ushort* Wg = W + (size_t)(bn + srow) * K + schunk;
    auto stage = [&](int buf, int k0) {
        gll16(Ag + k0, As + buf * 2048 + t * 8);
        gll16(Wg + k0, Bs + buf * 2048 + t * 8);
    };
    stage(0, 0);
    stage(1, BK);
    __syncthreads();   // full drain once

    f32x4 acc[2][2];
#pragma unroll
    for (int m = 0; m < 2; ++m)
#pragma unroll
        for (int n = 0; n < 2; ++n) acc[m][n] = (f32x4){0.f, 0.f, 0.f, 0.f};
    const int fr = lane & 15;
    const int rchunk = (((lane >> 4) ^ (fr & 3))) * 8;

    int cur = 0, nxt2 = 2;
    for (int s = 0; s < ksteps; ++s) {
        if (s + 1 < ksteps) {
            asm volatile("s_waitcnt vmcnt(2)" ::: "memory");
        } else {
            asm volatile("s_waitcnt vmcnt(0)" ::: "memory");
        }
        __builtin_amdgcn_s_barrier();
        if (s + 2 < ksteps) stage(nxt2, (s + 2) * BK);

        const ushort* Ab = As + cur * 2048;
        const ushort* Bb = Bs + cur * 2048;
        bf16x8 a0 = *(const bf16x8*)&Ab[(wm + fr) * BK + rchunk];
        bf16x8 a1 = *(const bf16x8*)&Ab[(wm + 16 + fr) * BK + rchunk];
        bf16x8 b0 = *(const bf16x8*)&Bb[(wn + fr) * BK + rchunk];
        bf16x8 b1 = *(const bf16x8*)&Bb[(wn + 16 + fr) * BK + rchunk];
        acc[0][0] = __builtin_amdgcn_mfma_f32_16x16x32_bf16(a0, b0, acc[0][0], 0, 0, 0);
        acc[0][1] = __builtin_amdgcn_mfma_f32_16x16x32_bf16(a0, b1, acc[0][1], 0, 0, 0);
        acc[1][0] = __builtin_amdgcn_mfma_f32_16x16x32_bf16(a1, b0, acc[1][0], 0, 0, 0);
        acc[1][1] = __builtin_amdgcn_mfma_f32_16x16x32_bf16(a1, b1, acc[1][1], 0, 0, 0);
        cur  = (cur  == 2) ? 0 : cur + 1;
        nxt2 = (nxt2 == 2) ? 0 : nxt2 + 1;
    }

    const int fq = (lane >> 4) * 4;
    float rs[8], rss[8];
#pragma unroll
    for (int i = 0; i < 8; ++i) { rs[i] = 0.f; rss[i] = 0.f; }

#pragma unroll
    for (int m = 0; m < 2; ++m) {
#pragma unroll
        for (int n = 0; n < 2; ++n) {
            const int col = bn + wn + n * 16 + fr;
            const float bvv = bias[col];
#pragma unroll
            for (int j = 0; j < 4; ++j) {
                const int rloc = wm + m * 16 + fq + j;
                const size_t off = (size_t)(bm + rloc) * N + col;
                float uu = acc[m][n][j] + bvv + res[off];
                if (ADD2) uu += res2[off];
                Cf[off] = uu;
                if (STATS) {
                    Cbb[off] = f2bf(uu);
                    rs[m * 4 + j]  += uu;
                    rss[m * 4 + j] += uu * uu;
                }
            }
        }
    }

    if (STATS) {
#pragma unroll
        for (int i = 0; i < 8; ++i) {
            rs[i]  += __shfl_xor(rs[i], 1);  rs[i]  += __shfl_xor(rs[i], 2);
            rs[i]  += __shfl_xor(rs[i], 4);  rs[i]  += __shfl_xor(rs[i], 8);
            rss[i] += __shfl_xor(rss[i], 1); rss[i] += __shfl_xor(rss[i], 2);
            rss[i] += __shfl_xor(rss[i], 4); rss[i] += __shfl_xor(rss[i], 8);
        }
        __syncthreads();   // all waves done with LDS bufs; reuse as rowred ok
        if ((lane & 15) == 0) {
#pragma unroll
            for (int m = 0; m < 2; ++m)
#pragma unroll
                for (int j = 0; j < 4; ++j)
                    rowred[(wm + m * 16 + fq + j) * 2 + (w & 1)] =
                        make_float2(rs[m * 4 + j], rss[m * 4 + j]);
        }
        __syncthreads();
        if (t < BM) {
            float2 a = rowred[t * 2], b = rowred[t * 2 + 1];
            statsOut[(size_t)(bm + t) * 8 + blockIdx.x] =
                make_float2(a.x + b.x, a.y + b.y);
        }
    }
}

#define RG_ARGS const ushort* __restrict__ A, const ushort* __restrict__ W,    \
    const float* __restrict__ bias, const float* __restrict__ res,             \
    const float* __restrict__ res2, float* __restrict__ Cf,                    \
    ushort* __restrict__ Cbb, float2* __restrict__ statsOut, int N, int K
#define DEF_RG(NAME, ADD2, STATS)                                              \
__global__ __launch_bounds__(256) void NAME(RG_ARGS) {                         \
    rgemm_body<ADD2, STATS>(A, W, bias, res, res2, Cf, Cbb, statsOut, N, K);   \
}
DEF_RG(outp_g,  false, true)    // attn out-proj + residual
DEF_RG(ff2_g,   false, true)    // ff2 + residual
DEF_RG(ff2l_g,  true,  true)    // layer-3 ff2: + residual + x
DEF_RG(mlp2_g,  false, false)   // final mlp2, K=2048

// Windowed 3x3 attention on 32x32 grid; one wave per (token,head) —
// round-7 proven config (max TLP for this latency-bound kernel).
__global__ __launch_bounds__(256) void attn_win_k(
    const ushort* __restrict__ qkv, ushort* __restrict__ o)
{
    const int wid  = (blockIdx.x * 256 + threadIdx.x) >> 6;
    const int lane = threadIdx.x & 63;
    const int hh = wid & 7;
    const int m  = wid >> 3;
    const int s  = m & 1023;
    const int y  = s >> 5, xq = s & 31;
    const int base_b = m & ~1023;

    const float qd = bf2f(qkv[(size_t)m * 1536 + hh * 64 + lane]);

    float sc[9];
    int   idx[9];
#pragma unroll
    for (int j = 0; j < 9; ++j) {
        const int dy = j / 3 - 1, dx = j % 3 - 1;
        const int yy = y + dy, xx = xq + dx;
        const bool ok = ((unsigned)yy < 32u) && ((unsigned)xx < 32u);
        const int ms = ok ? (base_b + (yy << 5) + xx) : m;
        idx[j] = ms;
        float pv = qd * bf2f(qkv[(size_t)ms * 1536 + 512 + hh * 64 + lane]);
#pragma unroll
        for (int off = 32; off; off >>= 1) pv += __shfl_xor(pv, off);
        sc[j] = ok ? pv * 0.125f : -1e30f;
    }
    float mx = sc[0];
#pragma unroll
    for (int j = 1; j < 9; ++j) mx = fmaxf(mx, sc[j]);
    float sum = 0.0f;
#pragma unroll
    for (int j = 0; j < 9; ++j) { sc[j] = expf(sc[j] - mx); sum += sc[j]; }
    const float inv = 1.0f / sum;
    float od = 0.0f;
#pragma unroll
    for (int j = 0; j < 9; ++j)
        od += sc[j] * bf2f(qkv[(size_t)idx[j] * 1536 + 1024 + hh * 64 + lane]);
    o[(size_t)m * 512 + hh * 64 + lane] = f2bf(od * inv);
}

// Merged weight conversion + x stats/cast. Blocks [0,16384) = cvt units,
// [16384,17408) = stats units.
__global__ __launch_bounds__(256) void cvtstats_k(
    const float* __restrict__ in_w, const float* __restrict__ in_b,
    const float* __restrict__ ln1_g, const float* __restrict__ ln1_b,
    const float* __restrict__ ff1_w, const float* __restrict__ ff1_b,
    const float* __restrict__ ln2_g, const float* __restrict__ ln2_b,
    const float* __restrict__ mlp_w1, const float* __restrict__ mlp_b1,
    const float* __restrict__ mlp_ln_g, const float* __restrict__ mlp_ln_b,
    const float* __restrict__ out_w, const float* __restrict__ ff2_w,
    const float* __restrict__ mlp_w2, ushort* __restrict__ wb,
    float* __restrict__ consts,
    const float* __restrict__ x, ushort* __restrict__ xb,
    float2* __restrict__ so)
{
    const int blk = blockIdx.x, t = threadIdx.x;
    if (blk >= 16384) {   // stats units
        const int u = blk - 16384;
        const int row  = u * 4 + (t >> 6);
        const int lane = t & 63;
        const float* xr = x + (size_t)row * 512 + lane * 8;
        float4 a0 = *(const float4*)xr;
        float4 a1 = *(const float4*)(xr + 4);
        bf16x8 pk;
        pk[0] = (short)f2bf(a0.x); pk[1] = (short)f2bf(a0.y);
        pk[2] = (short)f2bf(a0.z); pk[3] = (short)f2bf(a0.w);
        pk[4] = (short)f2bf(a1.x); pk[5] = (short)f2bf(a1.y);
        pk[6] = (short)f2bf(a1.z); pk[7] = (short)f2bf(a1.w);
        *(bf16x8*)&xb[(size_t)row * 512 + lane * 8] = pk;
        float s  = a0.x + a0.y + a0.z + a0.w + a1.x + a1.y + a1.z + a1.w;
        float ss = a0.x*a0.x + a0.y*a0.y + a0.z*a0.z + a0.w*a0.w
                 + a1.x*a1.x + a1.y*a1.y + a1.z*a1.z + a1.w*a1.w;
#pragma unroll
        for (int off = 32; off; off >>= 1) {
            s  += __shfl_xor(s, off);
            ss += __shfl_xor(ss, off);
        }
        if (lane == 0) so[(size_t)row * 8] = make_float2(s, ss);
        return;
    }
    __shared__ float redA[4], redB[4];
    const float *src, *g = nullptr, *b = nullptr, *bias = nullptr;
    ushort* dst; float *c2o = nullptr, *b2o = nullptr;
    int r = 0;
    if (blk < 6144) {                 // in_w, scaled by ln1_g[l]
        r = blk; const int l = r / 1536;
        src = in_w + (size_t)r * 512; dst = wb + (size_t)r * 512;
        g = ln1_g + l * 512; b = ln1_b + l * 512;
        bias = in_b; c2o = consts + 6144; b2o = consts;
    } else if (blk < 8192) {          // ff1_w, scaled by ln2_g[l]
        r = blk - 6144; const int l = r >> 9;
        src = ff1_w + (size_t)r * 512; dst = wb + 4194304 + (size_t)r * 512;
        g = ln2_g + l * 512; b = ln2_b + l * 512;
        bias = ff1_b; c2o = consts + 14336; b2o = consts + 12288;
    } else if (blk < 10240) {         // mlp_w1, scaled by mlp_ln_g
        r = blk - 8192;
        src = mlp_w1 + (size_t)r * 512; dst = wb + 6291456 + (size_t)r * 512;
        g = mlp_ln_g; b = mlp_ln_b;
        bias = mlp_b1; c2o = consts + 18432; b2o = consts + 16384;
    } else if (blk < 12288) {         // out_w plain
        const int q = blk - 10240;
        src = out_w + (size_t)q * 512; dst = wb + 3145728 + (size_t)q * 512;
    } else if (blk < 14336) {         // ff2_w plain
        const int q = blk - 12288;
        src = ff2_w + (size_t)q * 512; dst = wb + 5242880 + (size_t)q * 512;
    } else {                          // mlp_w2 plain
        const int q = blk - 14336;
        src = mlp_w2 + (size_t)q * 512; dst = wb + 7340032 + (size_t)q * 512;
    }
    float2 wv = *(const float2*)&src[t * 2];
    if (g) {
        float2 gv = *(const float2*)&g[t * 2];
        float2 bv = *(const float2*)&b[t * 2];
        const float w0 = wv.x * gv.x, w1 = wv.y * gv.y;
        ushort2 o; o.x = f2bf(w0); o.y = f2bf(w1);
        *(ushort2*)&dst[t * 2] = o;
        float sc2 = w0 + w1;
        float sc1 = bv.x * wv.x + bv.y * wv.y;
#pragma unroll
        for (int off = 32; off; off >>= 1) {
            sc2 += __shfl_xor(sc2, off);
            sc1 += __shfl_xor(sc1, off);
        }
        const int w_ = t >> 6;
        if ((t & 63) == 0) { redA[w_] = sc2; redB[w_] = sc1; }
        __syncthreads();
        if (t == 0) {
            c2o[r] = redA[0] + redA[1] + redA[2] + redA[3];
            b2o[r] = bias[r] + redB[0] + redB[1] + redB[2] + redB[3];
        }
    } else {
        ushort2 o; o.x = f2bf(wv.x); o.y = f2bf(wv.y);
        *(ushort2*)&dst[t * 2] = o;
    }
}

extern "C" void kernel_launch(void* const* d_in, const int* in_sizes, int n_in,
                              void* d_out, int out_size, void* d_ws, size_t ws_size,
                              hipStream_t stream) {
    const float* x        = (const float*)d_in[0];
    // d_in[1] = mask (unused; window hardcoded)
    const float* in_w     = (const float*)d_in[2];
    const float* in_b     = (const float*)d_in[3];
    const float* out_w    = (const float*)d_in[4];
    const float* out_b    = (const float*)d_in[5];
    const float* ln1_g    = (const float*)d_in[6];
    const float* ln1_b    = (const float*)d_in[7];
    const float* ln2_g    = (const float*)d_in[8];
    const float* ln2_b    = (const float*)d_in[9];
    const float* ff1_w    = (const float*)d_in[10];
    const float* ff1_b    = (const float*)d_in[11];
    const float* ff2_w    = (const float*)d_in[12];
    const float* ff2_b    = (const float*)d_in[13];
    const float* mlp_ln_g = (const float*)d_in[14];
    const float* mlp_ln_b = (const float*)d_in[15];
    const float* mlp_w1   = (const float*)d_in[16];
    const float* mlp_b1   = (const float*)d_in[17];
    const float* mlp_w2   = (const float*)d_in[18];
    const float* mlp_b2   = (const float*)d_in[19];
    float* out = (float*)d_out;

    const int M = 4096, E = 512;

    // ws layout (bytes): [0,16M) bf16 weights | [16M,+) consts |
    // [16.25M) stats_a | [16.5M) stats_b | [17M,25M) cur fp32 |
    // [25M,29M) curb bf16 | [29M,33M) b01 | [33M,45M) big (qkv)
    ushort* wb      = (ushort*)d_ws;
    float*  consts  = (float*)((char*)d_ws + (16u << 20));
    float2* stats_a = (float2*)((char*)d_ws + (16u << 20) + (256u << 10));
    float2* stats_b = stats_a + 32768;
    float*  cur     = (float*)((char*)d_ws + (17u << 20));
    ushort* curb    = (ushort*)((char*)d_ws + (25u << 20));
    ushort* b01     = (ushort*)((char*)d_ws + (29u << 20));
    ushort* big     = (ushort*)((char*)d_ws + (33u << 20));
    ushort* hidden  = b01;      // mlp hidden [M,2048] spans b01+big

    ushort* w_in  = wb;
    ushort* w_out = wb + 3145728;
    ushort* w_ff1 = wb + 4194304;
    ushort* w_ff2 = wb + 5242880;
    ushort* w_m1  = wb + 6291456;
    ushort* w_m2  = wb + 7340032;
    float* bias2_in = consts;            float* c2_in = consts + 6144;
    float* bias2_f1 = consts + 12288;    float* c2_f1 = consts + 14336;
    float* bias2_m1 = consts + 16384;    float* c2_m1 = consts + 18432;

    dim3 blk(256);
    cvtstats_k<<<17408, blk, 0, stream>>>(
        in_w, in_b, ln1_g, ln1_b, ff1_w, ff1_b, ln2_g, ln2_b,
        mlp_w1, mlp_b1, mlp_ln_g, mlp_ln_b, out_w, ff2_w, mlp_w2, wb, consts,
        x, curb, stats_a);

    for (int i = 0; i < 4; ++i) {
        const float* resid = (i == 0) ? x : cur;
        qkv_g<<<dim3(12, 64), blk, 0, stream>>>(
            curb, stats_a, (i == 0) ? 1 : 8,
            w_in + (size_t)i * 786432, bias2_in + i * 1536, c2_in + i * 1536,
            big, 1536);
        attn_win_k<<<(M * 8) / 4, blk, 0, stream>>>(big, b01);
        outp_g<<<dim3(8, 64), blk, 0, stream>>>(
            b01, w_out + (size_t)i * 262144, out_b + i * E, resid, nullptr,
            cur, curb, stats_b, E, E);
        ff1_g<<<dim3(8, 64), blk, 0, stream>>>(
            curb, stats_b, 8,
            w_ff1 + (size_t)i * 262144, bias2_f1 + i * E, c2_f1 + i * E,
            b01, E);
        if (i < 3) {
            ff2_g<<<dim3(8, 64), blk, 0, stream>>>(
                b01, w_ff2 + (size_t)i * 262144, ff2_b + i * E, cur, nullptr,
                cur, curb, stats_a, E, E);
        } else {
            ff2l_g<<<dim3(8, 64), blk, 0, stream>>>(
                b01, w_ff2 + (size_t)i * 262144, ff2_b + i * E, cur, x,
                out, curb, stats_a, E, E);
        }
    }

    mlp1_g<<<dim3(16, 64), blk, 0, stream>>>(
        curb, stats_a, 8, w_m1, bias2_m1, c2_m1, hidden, 2048);
    mlp2_g<<<dim3(8, 64), blk, 0, stream>>>(
        hidden, w_m2, mlp_b2, out, nullptr, out, nullptr, nullptr, E, 2048);
}

// Round 15
// 319.277 us; speedup vs baseline: 1.1601x; 1.0876x over previous
//
#include <hip/hip_runtime.h>
#include <math.h>

// ---------------------------------------------------------------------------
// Round 10: T1 XCD-aware tile swizzle on all GEMMs + attn. Consecutive
// blocks sharing an A row-slice currently round-robin across 8 XCDs ->
// each XCD refetches the slice (mlp2: 16MB x8 = 128MB). Remap
// f = (id%8)*(n/8) + id/8 (bijective, n%8==0) so same-slice blocks are
// consecutive on ONE XCD -> slice is a single L2 fetch; producer/consumer
// row-blocks also align across dispatches. Math identical to round 7/9.
// ---------------------------------------------------------------------------

typedef __attribute__((ext_vector_type(8))) short bf16x8;
typedef __attribute__((ext_vector_type(4))) float f32x4;

__device__ __forceinline__ float bf2f(ushort u) {
    union { uint i; float f; } c; c.i = ((uint)u) << 16; return c.f;
}
__device__ __forceinline__ ushort f2bf(float f) {
    union { float f; uint i; } c; c.f = f;
    uint u = c.i + 0x7fffu + ((c.i >> 16) & 1u);   // RNE
    return (ushort)(u >> 16);
}
__device__ __forceinline__ float gelu_f(float v) {
    return 0.5f * v * (1.0f + erff(v * 0.70710678118654752f));
}
__device__ __forceinline__ void gll16(const ushort* g, ushort* l) {
    __builtin_amdgcn_global_load_lds(
        (__attribute__((address_space(1))) void*)g,
        (__attribute__((address_space(3))) void*)l, 16, 0, 0);
}
// XCD-chunked bijective remap: hw linear id -> tile id such that
// consecutive tile ids land on the same XCD (hw assigns xcd = id % 8).
__device__ __forceinline__ int xcd_tile(int nblk) {
    const int id = blockIdx.y * gridDim.x + blockIdx.x;
    return (id & 7) * (nblk >> 3) + (id >> 3);
}

// ---------------------------------------------------------------------------
// LN-folded GEMM: Cb[M,N](bf16) = epi( rstd*(A@W'^T - mean*c2) + bias2 )
// K = 512 fixed. 3-buf depth-2 counted-vmcnt pipeline, swizzled reads.
// ---------------------------------------------------------------------------
template <int BM, int BN, int MODE>
__device__ __forceinline__ void lngemm_body(
    const ushort* __restrict__ A, const float2* __restrict__ stats, int nslots,
    const ushort* __restrict__ W, const float* __restrict__ bias2,
    const float* __restrict__ c2, ushort* __restrict__ Cb, int N)
{
    constexpr int BK = 32, K = 512, KSTEPS = K / BK;
    constexpr int FM = BM / 32, FN = BN / 32;
    constexpr int NL = BM / 64 + BN / 64;
    __shared__ ushort As[3 * BM * BK];
    __shared__ ushort Bs[3 * BN * BK];
    __shared__ float smean[BM], srstd[BM];

    const int t = threadIdx.x;
    const int lane = t & 63;
    const int w = t >> 6;
    const int wm = (w >> 1) * (BM / 2);
    const int wn = (w & 1) * (BN / 2);
    const int ncols = N / BN;
    const int f = xcd_tile(gridDim.x * gridDim.y);
    const int bn = (f % ncols) * BN;
    const int bm = (f / ncols) * BM;
    const int srow = t >> 2;
    const int schunk = ((t & 3) ^ (srow & 3)) * 8;   // pre-swizzled source

    const ushort* Ag = A + (size_t)(bm + srow) * K + schunk;
    const ushort* Wg = W + (size_t)(bn + srow) * K + schunk;
    auto stage = [&](int buf, int k0) {
#pragma unroll
        for (int i = 0; i < BM / 64; ++i)
            gll16(Ag + k0 + (size_t)(i * 64) * K, As + buf * (BM * BK) + i * 2048 + t * 8);
#pragma unroll
        for (int i = 0; i < BN / 64; ++i)
            gll16(Wg + k0 + (size_t)(i * 64) * K, Bs + buf * (BN * BK) + i * 2048 + t * 8);
    };
    stage(0, 0);
    stage(1, BK);

    if (t < BM) {     // per-row LN stats from producer partials
        float S = 0.f, SS = 0.f;
        for (int i = 0; i < nslots; ++i) {
            float2 pp = stats[(size_t)(bm + t) * 8 + i];
            S += pp.x; SS += pp.y;
        }
        const float mean = S * (1.0f / 512.0f);
        const float var  = SS * (1.0f / 512.0f) - mean * mean;
        smean[t] = mean;
        srstd[t] = rsqrtf(var + 1e-5f);
    }
    __syncthreads();   // full drain once: bufs 0,1 + stats resident

    f32x4 acc[FM][FN];
#pragma unroll
    for (int m = 0; m < FM; ++m)
#pragma unroll
        for (int n = 0; n < FN; ++n) acc[m][n] = (f32x4){0.f, 0.f, 0.f, 0.f};
    const int fr = lane & 15;
    const int rchunk = (((lane >> 4) ^ (fr & 3))) * 8;   // swizzled read chunk

    int cur = 0, nxt2 = 2;
    for (int s = 0; s < KSTEPS; ++s) {
        if (s + 1 < KSTEPS) {
            // wait until the oldest in-flight stage (NL loads) is retired
            if constexpr (NL == 2)      asm volatile("s_waitcnt vmcnt(2)" ::: "memory");
            else if constexpr (NL == 3) asm volatile("s_waitcnt vmcnt(3)" ::: "memory");
            else                        asm volatile("s_waitcnt vmcnt(4)" ::: "memory");
        } else {
            asm volatile("s_waitcnt vmcnt(0)" ::: "memory");
        }
        __builtin_amdgcn_s_barrier();
        if (s + 2 < KSTEPS) stage(nxt2, (s + 2) * BK);

        const ushort* Ab = As + cur * (BM * BK);
        const ushort* Bb = Bs + cur * (BN * BK);
        bf16x8 af[FM], bv[FN];
#pragma unroll
        for (int m = 0; m < FM; ++m)
            af[m] = *(const bf16x8*)&Ab[(wm + m * 16 + fr) * BK + rchunk];
#pragma unroll
        for (int n = 0; n < FN; ++n)
            bv[n] = *(const bf16x8*)&Bb[(wn + n * 16 + fr) * BK + rchunk];
#pragma unroll
        for (int m = 0; m < FM; ++m)
#pragma unroll
            for (int n = 0; n < FN; ++n)
                acc[m][n] = __builtin_amdgcn_mfma_f32_16x16x32_bf16(
                    af[m], bv[n], acc[m][n], 0, 0, 0);
        cur  = (cur  == 2) ? 0 : cur + 1;
        nxt2 = (nxt2 == 2) ? 0 : nxt2 + 1;
    }

    // epilogue: C/D layout col=lane&15, row=(lane>>4)*4+j
    const int fq = (lane >> 4) * 4;
#pragma unroll
    for (int m = 0; m < FM; ++m) {
#pragma unroll
        for (int n = 0; n < FN; ++n) {
            const int col = bn + wn + n * 16 + fr;
            const float c2v = c2[col];
            const float b2v = bias2[col];
#pragma unroll
            for (int j = 0; j < 4; ++j) {
                const int rloc = wm + m * 16 + fq + j;
                float uu = srstd[rloc] * (acc[m][n][j] - smean[rloc] * c2v) + b2v;
                if (MODE == 1) uu = gelu_f(uu);
                Cb[(size_t)(bm + rloc) * N + col] = f2bf(uu);
            }
        }
    }
}

#define LNG_ARGS const ushort* __restrict__ A, const float2* __restrict__ stats, \
    int nslots, const ushort* __restrict__ W, const float* __restrict__ bias2,   \
    const float* __restrict__ c2, ushort* __restrict__ Cb, int N
#define DEF_LNG(NAME, BM, BN, MODE)                                              \
__global__ __launch_bounds__(256) void NAME(LNG_ARGS) {                          \
    lngemm_body<BM, BN, MODE>(A, stats, nslots, W, bias2, c2, Cb, N);            \
}
DEF_LNG(qkv_g,   64, 128, 0)   // N=1536, 768 blocks
DEF_LNG(ff1_g,   64,  64, 1)   // N=512, gelu
DEF_LNG(mlp1_g,  64, 128, 1)   // N=2048, gelu, 1024 blocks

// ---------------------------------------------------------------------------
// Residual GEMM 64x64: u = A@W^T + bias + res (+res2). Runtime K.
// 3-buf depth-2, 25KB LDS -> 6 blocks/CU. XCD-swizzled tiles.
// ---------------------------------------------------------------------------
template <bool ADD2, bool STATS>
__device__ __forceinline__ void rgemm_body(
    const ushort* __restrict__ A, const ushort* __restrict__ W,
    const float* __restrict__ bias, const float* __restrict__ res,
    const float* __restrict__ res2, float* __restrict__ Cf,
    ushort* __restrict__ Cbb, float2* __restrict__ statsOut, int N, int K)
{
    constexpr int BM = 64, BN = 64, BK = 32;
    __shared__ ushort As[3 * BM * BK];
    __shared__ ushort Bs[3 * BN * BK];
    __shared__ float2 rowred[BM * 2];

    const int t = threadIdx.x;
    const int lane = t & 63;
    const int w = t >> 6;
    const int wm = (w >> 1) * 32;
    const int wn = (w & 1) * 32;
    const int ncols = N / BN;
    const int f = xcd_tile(gridDim.x * gridDim.y);
    const int tn = f % ncols;
    const int bn = tn * BN;
    const int bm = (f / ncols) * BM;
    const int srow = t >> 2;
    const int schunk = ((t & 3) ^ (srow & 3)) * 8;
    const int ksteps = K / BK;

    const ushort* Ag = A + (size_t)(bm + srow) * K + schunk;
    const ushort* Wg = W + (size_t)(bn + srow) * K + schunk;
    auto stage = [&](int buf, int k0) {
        gll16(Ag + k0, As + buf * 2048 + t * 8);
        gll16(Wg + k0, Bs + buf * 2048 + t * 8);
    };
    stage(0, 0);
    stage(1, BK);
    __syncthreads();   // full drain once

    f32x4 acc[2][2];
#pragma unroll
    for (int m = 0; m < 2; ++m)
#pragma unroll
        for (int n = 0; n < 2; ++n) acc[m][n] = (f32x4){0.f, 0.f, 0.f, 0.f};
    const int fr = lane & 15;
    const int rchunk = (((lane >> 4) ^ (fr & 3))) * 8;

    int cur = 0, nxt2 = 2;
    for (int s = 0; s < ksteps; ++s) {
        if (s + 1 < ksteps) {
            asm volatile("s_waitcnt vmcnt(2)" ::: "memory");
        } else {
            asm volatile("s_waitcnt vmcnt(0)" ::: "memory");
        }
        __builtin_amdgcn_s_barrier();
        if (s + 2 < ksteps) stage(nxt2, (s + 2) * BK);

        const ushort* Ab = As + cur * 2048;
        const ushort* Bb = Bs + cur * 2048;
        bf16x8 a0 = *(const bf16x8*)&Ab[(wm + fr) * BK + rchunk];
        bf16x8 a1 = *(const bf16x8*)&Ab[(wm + 16 + fr) * BK + rchunk];
        bf16x8 b0 = *(const bf16x8*)&Bb[(wn + fr) * BK + rchunk];
        bf16x8 b1 = *(const bf16x8*)&Bb[(wn + 16 + fr) * BK + rchunk];
        acc[0][0] = __builtin_amdgcn_mfma_f32_16x16x32_bf16(a0, b0, acc[0][0], 0, 0, 0);
        acc[0][1] = __builtin_amdgcn_mfma_f32_16x16x32_bf16(a0, b1, acc[0][1], 0, 0, 0);
        acc[1][0] = __builtin_amdgcn_mfma_f32_16x16x32_bf16(a1, b0, acc[1][0], 0, 0, 0);
        acc[1][1] = __builtin_amdgcn_mfma_f32_16x16x32_bf16(a1, b1, acc[1][1], 0, 0, 0);
        cur  = (cur  == 2) ? 0 : cur + 1;
        nxt2 = (nxt2 == 2) ? 0 : nxt2 + 1;
    }

    const int fq = (lane >> 4) * 4;
    float rs[8], rss[8];
#pragma unroll
    for (int i = 0; i < 8; ++i) { rs[i] = 0.f; rss[i] = 0.f; }

#pragma unroll
    for (int m = 0; m < 2; ++m) {
#pragma unroll
        for (int n = 0; n < 2; ++n) {
            const int col = bn + wn + n * 16 + fr;
            const float bvv = bias[col];
#pragma unroll
            for (int j = 0; j < 4; ++j) {
                const int rloc = wm + m * 16 + fq + j;
                const size_t off = (size_t)(bm + rloc) * N + col;
                float uu = acc[m][n][j] + bvv + res[off];
                if (ADD2) uu += res2[off];
                Cf[off] = uu;
                if (STATS) {
                    Cbb[off] = f2bf(uu);
                    rs[m * 4 + j]  += uu;
                    rss[m * 4 + j] += uu * uu;
                }
            }
        }
    }

    if (STATS) {
#pragma unroll
        for (int i = 0; i < 8; ++i) {
            rs[i]  += __shfl_xor(rs[i], 1);  rs[i]  += __shfl_xor(rs[i], 2);
            rs[i]  += __shfl_xor(rs[i], 4);  rs[i]  += __shfl_xor(rs[i], 8);
            rss[i] += __shfl_xor(rss[i], 1); rss[i] += __shfl_xor(rss[i], 2);
            rss[i] += __shfl_xor(rss[i], 4); rss[i] += __shfl_xor(rss[i], 8);
        }
        __syncthreads();   // all waves done with LDS bufs; reuse as rowred ok
        if ((lane & 15) == 0) {
#pragma unroll
            for (int m = 0; m < 2; ++m)
#pragma unroll
                for (int j = 0; j < 4; ++j)
                    rowred[(wm + m * 16 + fq + j) * 2 + (w & 1)] =
                        make_float2(rs[m * 4 + j], rss[m * 4 + j]);
        }
        __syncthreads();
        if (t < BM) {
            float2 a = rowred[t * 2], b = rowred[t * 2 + 1];
            statsOut[(size_t)(bm + t) * 8 + tn] =
                make_float2(a.x + b.x, a.y + b.y);
        }
    }
}

#define RG_ARGS const ushort* __restrict__ A, const ushort* __restrict__ W,    \
    const float* __restrict__ bias, const float* __restrict__ res,             \
    const float* __restrict__ res2, float* __restrict__ Cf,                    \
    ushort* __restrict__ Cbb, float2* __restrict__ statsOut, int N, int K
#define DEF_RG(NAME, ADD2, STATS)                                              \
__global__ __launch_bounds__(256) void NAME(RG_ARGS) {                         \
    rgemm_body<ADD2, STATS>(A, W, bias, res, res2, Cf, Cbb, statsOut, N, K);   \
}
DEF_RG(outp_g,  false, true)    // attn out-proj + residual
DEF_RG(ff2_g,   false, true)    // ff2 + residual
DEF_RG(ff2l_g,  true,  true)    // layer-3 ff2: + residual + x
DEF_RG(mlp2_g,  false, false)   // final mlp2, K=2048

// Windowed 3x3 attention; one wave per (token,head); XCD-chunked block remap
// so neighbor tokens' qkv rows stay XCD-local.
__global__ __launch_bounds__(256) void attn_win_k(
    const ushort* __restrict__ qkv, ushort* __restrict__ o)
{
    const int nblk = gridDim.x;
    const int bid  = blockIdx.x;
    const int fb   = (bid & 7) * (nblk >> 3) + (bid >> 3);
    const int wid  = (fb * 256 + threadIdx.x) >> 6;
    const int lane = threadIdx.x & 63;
    const int hh = wid & 7;
    const int m  = wid >> 3;
    const int s  = m & 1023;
    const int y  = s >> 5, xq = s & 31;
    const int base_b = m & ~1023;

    const float qd = bf2f(qkv[(size_t)m * 1536 + hh * 64 + lane]);

    float sc[9];
    int   idx[9];
#pragma unroll
    for (int j = 0; j < 9; ++j) {
        const int dy = j / 3 - 1, dx = j % 3 - 1;
        const int yy = y + dy, xx = xq + dx;
        const bool ok = ((unsigned)yy < 32u) && ((unsigned)xx < 32u);
        const int ms = ok ? (base_b + (yy << 5) + xx) : m;
        idx[j] = ms;
        float pv = qd * bf2f(qkv[(size_t)ms * 1536 + 512 + hh * 64 + lane]);
#pragma unroll
        for (int off = 32; off; off >>= 1) pv += __shfl_xor(pv, off);
        sc[j] = ok ? pv * 0.125f : -1e30f;
    }
    float mx = sc[0];
#pragma unroll
    for (int j = 1; j < 9; ++j) mx = fmaxf(mx, sc[j]);
    float sum = 0.0f;
#pragma unroll
    for (int j = 0; j < 9; ++j) { sc[j] = expf(sc[j] - mx); sum += sc[j]; }
    const float inv = 1.0f / sum;
    float od = 0.0f;
#pragma unroll
    for (int j = 0; j < 9; ++j)
        od += sc[j] * bf2f(qkv[(size_t)idx[j] * 1536 + 1024 + hh * 64 + lane]);
    o[(size_t)m * 512 + hh * 64 + lane] = f2bf(od * inv);
}

// Merged weight conversion + x stats/cast. Blocks [0,16384) = cvt units,
// [16384,17408) = stats units.
__global__ __launch_bounds__(256) void cvtstats_k(
    const float* __restrict__ in_w, const float* __restrict__ in_b,
    const float* __restrict__ ln1_g, const float* __restrict__ ln1_b,
    const float* __restrict__ ff1_w, const float* __restrict__ ff1_b,
    const float* __restrict__ ln2_g, const float* __restrict__ ln2_b,
    const float* __restrict__ mlp_w1, const float* __restrict__ mlp_b1,
    const float* __restrict__ mlp_ln_g, const float* __restrict__ mlp_ln_b,
    const float* __restrict__ out_w, const float* __restrict__ ff2_w,
    const float* __restrict__ mlp_w2, ushort* __restrict__ wb,
    float* __restrict__ consts,
    const float* __restrict__ x, ushort* __restrict__ xb,
    float2* __restrict__ so)
{
    const int blk = blockIdx.x, t = threadIdx.x;
    if (blk >= 16384) {   // stats units
        const int u = blk - 16384;
        const int row  = u * 4 + (t >> 6);
        const int lane = t & 63;
        const float* xr = x + (size_t)row * 512 + lane * 8;
        float4 a0 = *(const float4*)xr;
        float4 a1 = *(const float4*)(xr + 4);
        bf16x8 pk;
        pk[0] = (short)f2bf(a0.x); pk[1] = (short)f2bf(a0.y);
        pk[2] = (short)f2bf(a0.z); pk[3] = (short)f2bf(a0.w);
        pk[4] = (short)f2bf(a1.x); pk[5] = (short)f2bf(a1.y);
        pk[6] = (short)f2bf(a1.z); pk[7] = (short)f2bf(a1.w);
        *(bf16x8*)&xb[(size_t)row * 512 + lane * 8] = pk;
        float s  = a0.x + a0.y + a0.z + a0.w + a1.x + a1.y + a1.z + a1.w;
        float ss = a0.x*a0.x + a0.y*a0.y + a0.z*a0.z + a0.w*a0.w
                 + a1.x*a1.x + a1.y*a1.y + a1.z*a1.z + a1.w*a1.w;
#pragma unroll
        for (int off = 32; off; off >>= 1) {
            s  += __shfl_xor(s, off);
            ss += __shfl_xor(ss, off);
        }
        if (lane == 0) so[(size_t)row * 8] = make_float2(s, ss);
        return;
    }
    __shared__ float redA[4], redB[4];
    const float *src, *g = nullptr, *b = nullptr, *bias = nullptr;
    ushort* dst; float *c2o = nullptr, *b2o = nullptr;
    int r = 0;
    if (blk < 6144) {                 // in_w, scaled by ln1_g[l]
        r = blk; const int l = r / 1536;
        src = in_w + (size_t)r * 512; dst = wb + (size_t)r * 512;
        g = ln1_g + l * 512; b = ln1_b + l * 512;
        bias = in_b; c2o = consts + 6144; b2o = consts;
    } else if (blk < 8192) {          // ff1_w, scaled by ln2_g[l]
        r = blk - 6144; const int l = r >> 9;
        src = ff1_w + (size_t)r * 512; dst = wb + 4194304 + (size_t)r * 512;
        g = ln2_g + l * 512; b = ln2_b + l * 512;
        bias = ff1_b; c2o = consts + 14336; b2o = consts + 12288;
    } else if (blk < 10240) {         // mlp_w1, scaled by mlp_ln_g
        r = blk - 8192;
        src = mlp_w1 + (size_t)r * 512; dst = wb + 6291456 + (size_t)r * 512;
        g = mlp_ln_g; b = mlp_ln_b;
        bias = mlp_b1; c2o = consts + 18432; b2o = consts + 16384;
    } else if (blk < 12288) {         // out_w plain
        const int q = blk - 10240;
        src = out_w + (size_t)q * 512; dst = wb + 3145728 + (size_t)q * 512;
    } else if (blk < 14336) {         // ff2_w plain
        const int q = blk - 12288;
        src = ff2_w + (size_t)q * 512; dst = wb + 5242880 + (size_t)q * 512;
    } else {                          // mlp_w2 plain
        const int q = blk - 14336;
        src = mlp_w2 + (size_t)q * 512; dst = wb + 7340032 + (size_t)q * 512;
    }
    float2 wv = *(const float2*)&src[t * 2];
    if (g) {
        float2 gv = *(const float2*)&g[t * 2];
        float2 bv = *(const float2*)&b[t * 2];
        const float w0 = wv.x * gv.x, w1 = wv.y * gv.y;
        ushort2 o; o.x = f2bf(w0); o.y = f2bf(w1);
        *(ushort2*)&dst[t * 2] = o;
        float sc2 = w0 + w1;
        float sc1 = bv.x * wv.x + bv.y * wv.y;
#pragma unroll
        for (int off = 32; off; off >>= 1) {
            sc2 += __shfl_xor(sc2, off);
            sc1 += __shfl_xor(sc1, off);
        }
        const int w_ = t >> 6;
        if ((t & 63) == 0) { redA[w_] = sc2; redB[w_] = sc1; }
        __syncthreads();
        if (t == 0) {
            c2o[r] = redA[0] + redA[1] + redA[2] + redA[3];
            b2o[r] = bias[r] + redB[0] + redB[1] + redB[2] + redB[3];
        }
    } else {
        ushort2 o; o.x = f2bf(wv.x); o.y = f2bf(wv.y);
        *(ushort2*)&dst[t * 2] = o;
    }
}

extern "C" void kernel_launch(void* const* d_in, const int* in_sizes, int n_in,
                              void* d_out, int out_size, void* d_ws, size_t ws_size,
                              hipStream_t stream) {
    const float* x        = (const float*)d_in[0];
    // d_in[1] = mask (unused; window hardcoded)
    const float* in_w     = (const float*)d_in[2];
    const float* in_b     = (const float*)d_in[3];
    const float* out_w    = (const float*)d_in[4];
    const float* out_b    = (const float*)d_in[5];
    const float* ln1_g    = (const float*)d_in[6];
    const float* ln1_b    = (const float*)d_in[7];
    const float* ln2_g    = (const float*)d_in[8];
    const float* ln2_b    = (const float*)d_in[9];
    const float* ff1_w    = (const float*)d_in[10];
    const float* ff1_b    = (const float*)d_in[11];
    const float* ff2_w    = (const float*)d_in[12];
    const float* ff2_b    = (const float*)d_in[13];
    const float* mlp_ln_g = (const float*)d_in[14];
    const float* mlp_ln_b = (const float*)d_in[15];
    const float* mlp_w1   = (const float*)d_in[16];
    const float* mlp_b1   = (const float*)d_in[17];
    const float* mlp_w2   = (const float*)d_in[18];
    const float* mlp_b2   = (const float*)d_in[19];
    float* out = (float*)d_out;

    const int M = 4096, E = 512;

    // ws layout (bytes): [0,16M) bf16 weights | [16M,+) consts |
    // [16.25M) stats_a | [16.5M) stats_b | [17M,25M) cur fp32 |
    // [25M,29M) curb bf16 | [29M,33M) b01 | [33M,45M) big (qkv)
    ushort* wb      = (ushort*)d_ws;
    float*  consts  = (float*)((char*)d_ws + (16u << 20));
    float2* stats_a = (float2*)((char*)d_ws + (16u << 20) + (256u << 10));
    float2* stats_b = stats_a + 32768;
    float*  cur     = (float*)((char*)d_ws + (17u << 20));
    ushort* curb    = (ushort*)((char*)d_ws + (25u << 20));
    ushort* b01     = (ushort*)((char*)d_ws + (29u << 20));
    ushort* big     = (ushort*)((char*)d_ws + (33u << 20));
    ushort* hidden  = b01;      // mlp hidden [M,2048] spans b01+big

    ushort* w_in  = wb;
    ushort* w_out = wb + 3145728;
    ushort* w_ff1 = wb + 4194304;
    ushort* w_ff2 = wb + 5242880;
    ushort* w_m1  = wb + 6291456;
    ushort* w_m2  = wb + 7340032;
    float* bias2_in = consts;            float* c2_in = consts + 6144;
    float* bias2_f1 = consts + 12288;    float* c2_f1 = consts + 14336;
    float* bias2_m1 = consts + 16384;    float* c2_m1 = consts + 18432;

    dim3 blk(256);
    cvtstats_k<<<17408, blk, 0, stream>>>(
        in_w, in_b, ln1_g, ln1_b, ff1_w, ff1_b, ln2_g, ln2_b,
        mlp_w1, mlp_b1, mlp_ln_g, mlp_ln_b, out_w, ff2_w, mlp_w2, wb, consts,
        x, curb, stats_a);

    for (int i = 0; i < 4; ++i) {
        const float* resid = (i == 0) ? x : cur;
        qkv_g<<<dim3(12, 64), blk, 0, stream>>>(
            curb, stats_a, (i == 0) ? 1 : 8,
            w_in + (size_t)i * 786432, bias2_in + i * 1536, c2_in + i * 1536,
            big, 1536);
        attn_win_k<<<(M * 8) / 4, blk, 0, stream>>>(big, b01);
        outp_g<<<dim3(8, 64), blk, 0, stream>>>(
            b01, w_out + (size_t)i * 262144, out_b + i * E, resid, nullptr,
            cur, curb, stats_b, E, E);
        ff1_g<<<dim3(8, 64), blk, 0, stream>>>(
            curb, stats_b, 8,
            w_ff1 + (size_t)i * 262144, bias2_f1 + i * E, c2_f1 + i * E,
            b01, E);
        if (i < 3) {
            ff2_g<<<dim3(8, 64), blk, 0, stream>>>(
                b01, w_ff2 + (size_t)i * 262144, ff2_b + i * E, cur, nullptr,
                cur, curb, stats_a, E, E);
        } else {
            ff2l_g<<<dim3(8, 64), blk, 0, stream>>>(
                b01, w_ff2 + (size_t)i * 262144, ff2_b + i * E, cur, x,
                out, curb, stats_a, E, E);
        }
    }

    mlp1_g<<<dim3(16, 64), blk, 0, stream>>>(
        curb, stats_a, 8, w_m1, bias2_m1, c2_m1, hidden, 2048);
    mlp2_g<<<dim3(8, 64), blk, 0, stream>>>(
        hidden, w_m2, mlp_b2, out, nullptr, out, nullptr, nullptr, E, 2048);
}